// Round 1
// baseline (1547.988 us; speedup 1.0000x reference)
//
#include <hip/hip_runtime.h>
#include <cstdint>
#include <cstddef>

#define N_NODES 50000
#define N_EDGES 800000
#define F_IN    512
#define H_DIM   128
#define C_OUT   40
#define TOT_E   (N_EDGES + N_NODES)

// ----------------------------- setup kernels -------------------------------

__global__ void init_nodes_k(float* deg, int* cnt, int n) {
  int i = blockIdx.x * blockDim.x + threadIdx.x;
  if (i < n) { deg[i] = 1.0f; cnt[i] = 1; }   // self-loop: weight 1, count 1
}

__global__ void edge_hist_k(const int* __restrict__ dst, const float* __restrict__ ew,
                            float* deg, int* cnt, int e) {
  int i = blockIdx.x * blockDim.x + threadIdx.x;
  if (i < e) {
    int d = dst[i];
    atomicAdd(&deg[d], ew[i]);
    atomicAdd(&cnt[d], 1);
  }
}

__global__ void dinv_k(float* deg, int n) {
  int i = blockIdx.x * blockDim.x + threadIdx.x;
  if (i < n) deg[i] = rsqrtf(deg[i]);   // deg >= 1 always (self-loop)
}

// single-block exclusive scan over counts -> row_ptr (N=50000, 1024 threads x 49)
__global__ __launch_bounds__(1024) void scan_k(const int* __restrict__ cnt,
                                               int* row_ptr, int* cursor, int n) {
  __shared__ int sums[1024];
  int t = threadIdx.x;
  int chunk = (n + 1023) >> 10;
  int base = t * chunk;
  int s = 0;
  for (int i = 0; i < chunk; ++i) {
    int idx = base + i;
    if (idx < n) s += cnt[idx];
  }
  sums[t] = s;
  __syncthreads();
  for (int off = 1; off < 1024; off <<= 1) {
    int v = (t >= off) ? sums[t - off] : 0;
    __syncthreads();
    sums[t] += v;
    __syncthreads();
  }
  int run = (t == 0) ? 0 : sums[t - 1];
  for (int i = 0; i < chunk; ++i) {
    int idx = base + i;
    if (idx < n) { row_ptr[idx] = run; cursor[idx] = run; run += cnt[idx]; }
  }
  if (t == 1023) row_ptr[n] = sums[1023];
}

// scatter edges (and self-loops) into CSR-by-dst, computing norm on the fly
__global__ void scatter_k(const int* __restrict__ src, const int* __restrict__ dst,
                          const float* __restrict__ ew, const float* __restrict__ dinv,
                          int* cursor, int* ccol, float* cw, int e, int n) {
  int i = blockIdx.x * blockDim.x + threadIdx.x;
  if (i < e) {
    int s = src[i], d = dst[i];
    float w = dinv[s] * ew[i] * dinv[d];
    int pos = atomicAdd(&cursor[d], 1);
    ccol[pos] = s;
    cw[pos] = w;
  } else if (i < e + n) {
    int v = i - e;
    float di = dinv[v];
    int pos = atomicAdd(&cursor[v], 1);
    ccol[pos] = v;
    cw[pos] = di * di;
  }
}

// ------------------------- dense fp32 GEMM, Ncol=128 -----------------------
// C[M,128] = A[M,K] @ W[K,128] (+ bias). Tile 64 rows x 128 cols, BK=32.
// Per thread: 4x8 micro-tile. A staged transposed (stride 65 -> conflict-free).
__global__ __launch_bounds__(256) void gemm_n128_k(
    const float* __restrict__ A, const float* __restrict__ W,
    const float* __restrict__ bias, float* __restrict__ C,
    int M, int K) {
  __shared__ float As[32][65];
  __shared__ float Ws[32][128];
  const int t  = threadIdx.x;
  const int m0 = blockIdx.x * 64;
  const int tr = t >> 4;   // 0..15 row-group (4 rows)
  const int tc = t & 15;   // 0..15 col-group (8 cols)
  float acc[4][8];
#pragma unroll
  for (int i = 0; i < 4; ++i)
#pragma unroll
    for (int j = 0; j < 8; ++j) acc[i][j] = 0.0f;

  for (int k0 = 0; k0 < K; k0 += 32) {
    // stage A 64x32 (float4 loads, transpose into As[k][m])
#pragma unroll
    for (int i = 0; i < 2; ++i) {
      int e4 = t + i * 256;         // 0..511
      int m  = e4 >> 3;             // 0..63
      int k4 = e4 & 7;              // 0..7
      int gm = m0 + m; if (gm >= M) gm = M - 1;
      float4 a = *(const float4*)&A[(size_t)gm * K + k0 + (k4 << 2)];
      As[(k4 << 2) + 0][m] = a.x;
      As[(k4 << 2) + 1][m] = a.y;
      As[(k4 << 2) + 2][m] = a.z;
      As[(k4 << 2) + 3][m] = a.w;
    }
    // stage W 32x128 (float4 direct)
#pragma unroll
    for (int i = 0; i < 4; ++i) {
      int e4 = t + i * 256;         // 0..1023
      int k  = e4 >> 5;             // 0..31
      int c4 = e4 & 31;             // 0..31
      *(float4*)&Ws[k][c4 << 2] = *(const float4*)&W[(size_t)(k0 + k) * 128 + (c4 << 2)];
    }
    __syncthreads();
#pragma unroll
    for (int k = 0; k < 32; ++k) {
      float av[4];
#pragma unroll
      for (int i = 0; i < 4; ++i) av[i] = As[k][(tr << 2) + i];
      float wv[8];
      *(float4*)&wv[0] = *(const float4*)&Ws[k][tc << 3];
      *(float4*)&wv[4] = *(const float4*)&Ws[k][(tc << 3) + 4];
#pragma unroll
      for (int i = 0; i < 4; ++i)
#pragma unroll
        for (int j = 0; j < 8; ++j)
          acc[i][j] += av[i] * wv[j];
    }
    __syncthreads();
  }
  float b[8] = {0, 0, 0, 0, 0, 0, 0, 0};
  if (bias) {
    float4 b0 = *(const float4*)&bias[tc << 3];
    float4 b1 = *(const float4*)&bias[(tc << 3) + 4];
    b[0] = b0.x; b[1] = b0.y; b[2] = b0.z; b[3] = b0.w;
    b[4] = b1.x; b[5] = b1.y; b[6] = b1.z; b[7] = b1.w;
  }
#pragma unroll
  for (int i = 0; i < 4; ++i) {
    int gm = m0 + (tr << 2) + i;
    if (gm < M) {
      float4 r0 = make_float4(acc[i][0] + b[0], acc[i][1] + b[1],
                              acc[i][2] + b[2], acc[i][3] + b[3]);
      float4 r1 = make_float4(acc[i][4] + b[4], acc[i][5] + b[5],
                              acc[i][6] + b[6], acc[i][7] + b[7]);
      *(float4*)&C[(size_t)gm * 128 + (tc << 3)]     = r0;
      *(float4*)&C[(size_t)gm * 128 + (tc << 3) + 4] = r1;
    }
  }
}

// ------------------ sparse aggregation: out = CSR(hw) + bias ---------------
// one wave per node; lane holds float2 (128 features / 64 lanes)
__global__ __launch_bounds__(256) void aggregate_k(
    const int* __restrict__ row_ptr, const int* __restrict__ ccol,
    const float* __restrict__ cw, const float* __restrict__ hw,
    const float* __restrict__ bias, float* __restrict__ out, int n) {
  int lane = threadIdx.x & 63;
  int node = (blockIdx.x << 2) + (threadIdx.x >> 6);
  if (node >= n) return;
  int beg = row_ptr[node];
  int end = row_ptr[node + 1];
  const float2* hw2 = (const float2*)hw;
  float2 acc = make_float2(0.f, 0.f);
  int j = beg;
  for (; j + 1 < end; j += 2) {
    int c0 = ccol[j], c1 = ccol[j + 1];
    float w0 = cw[j], w1 = cw[j + 1];
    float2 v0 = hw2[((size_t)c0 << 6) + lane];
    float2 v1 = hw2[((size_t)c1 << 6) + lane];
    acc.x += w0 * v0.x; acc.y += w0 * v0.y;
    acc.x += w1 * v1.x; acc.y += w1 * v1.y;
  }
  for (; j < end; ++j) {
    int c = ccol[j]; float w = cw[j];
    float2 v = hw2[((size_t)c << 6) + lane];
    acc.x += w * v.x; acc.y += w * v.y;
  }
  float2 b = ((const float2*)bias)[lane];
  acc.x += b.x; acc.y += b.y;
  ((float2*)out)[((size_t)node << 6) + lane] = acc;
}

// ------------- output accumulation: out (+)= A[M,128] @ Wb[128,40] ---------
// tile 128 rows x 40 cols; per thread 4 rows x 5 cols
__global__ __launch_bounds__(256) void out_accum_k(
    const float* __restrict__ A, const float* __restrict__ Wb,
    const float* __restrict__ bias, float* __restrict__ out,
    int M, int init) {
  __shared__ float As[32][129];
  __shared__ float Ws[32][40];
  const int t  = threadIdx.x;
  const int m0 = blockIdx.x * 128;
  const int ng = t >> 3;   // 0..31 row-group (4 rows)
  const int cg = t & 7;    // 0..7 col-group (5 cols)
  float acc[4][5];
#pragma unroll
  for (int i = 0; i < 4; ++i)
#pragma unroll
    for (int j = 0; j < 5; ++j) acc[i][j] = 0.0f;

  for (int k0 = 0; k0 < 128; k0 += 32) {
    // stage A 128x32 transposed (1024 float4, 4 per thread)
#pragma unroll
    for (int i = 0; i < 4; ++i) {
      int e4 = t + i * 256;        // 0..1023
      int m  = e4 >> 3;            // 0..127
      int k4 = e4 & 7;             // 0..7
      int gm = m0 + m; if (gm >= M) gm = M - 1;
      float4 a = *(const float4*)&A[(size_t)gm * 128 + k0 + (k4 << 2)];
      As[(k4 << 2) + 0][m] = a.x;
      As[(k4 << 2) + 1][m] = a.y;
      As[(k4 << 2) + 2][m] = a.z;
      As[(k4 << 2) + 3][m] = a.w;
    }
    // stage W 32x40 = 1280 floats
#pragma unroll
    for (int i = 0; i < 5; ++i) {
      int e = t + i * 256;
      if (e < 1280) {
        int k = e / 40; int c = e - k * 40;
        Ws[k][c] = Wb[(size_t)(k0 + k) * 40 + c];
      }
    }
    __syncthreads();
#pragma unroll
    for (int k = 0; k < 32; ++k) {
      float av[4];
#pragma unroll
      for (int i = 0; i < 4; ++i) av[i] = As[k][(ng << 2) + i];
      float wv[5];
#pragma unroll
      for (int j = 0; j < 5; ++j) wv[j] = Ws[k][cg * 5 + j];
#pragma unroll
      for (int i = 0; i < 4; ++i)
#pragma unroll
        for (int j = 0; j < 5; ++j)
          acc[i][j] += av[i] * wv[j];
    }
    __syncthreads();
  }
#pragma unroll
  for (int i = 0; i < 4; ++i) {
    int gm = m0 + (ng << 2) + i;
    if (gm < M) {
#pragma unroll
      for (int j = 0; j < 5; ++j) {
        int c = cg * 5 + j;
        float v = acc[i][j];
        v += init ? bias[c] : out[(size_t)gm * 40 + c];
        out[(size_t)gm * 40 + c] = v;
      }
    }
  }
}

// ------------------------------- launcher ----------------------------------

extern "C" void kernel_launch(void* const* d_in, const int* in_sizes, int n_in,
                              void* d_out, int out_size, void* d_ws, size_t ws_size,
                              hipStream_t stream) {
  const float* x     = (const float*)d_in[0];
  const int*   eidx  = (const int*)  d_in[1];
  const float* ew    = (const float*)d_in[2];
  const float* W_in  = (const float*)d_in[3];
  const float* b_in  = (const float*)d_in[4];
  const float* W_gcn = (const float*)d_in[5];
  const float* b_gcn = (const float*)d_in[6];
  const float* W_out = (const float*)d_in[7];
  const float* b_out = (const float*)d_in[8];
  float* out = (float*)d_out;

  const int* src = eidx;             // edge_index[0]
  const int* dst = eidx + N_EDGES;   // edge_index[1]

  char* ws = (char*)d_ws;
  size_t off = 0;
  auto alloc = [&](size_t bytes) -> void* {
    void* p = ws + off;
    off += (bytes + 255) & ~(size_t)255;
    return p;
  };
  float* deg    = (float*)alloc((size_t)N_NODES * 4);     // becomes dinv
  int*   cnt    = (int*)  alloc((size_t)N_NODES * 4);
  int*   rowp   = (int*)  alloc((size_t)(N_NODES + 1) * 4);
  int*   cursor = (int*)  alloc((size_t)N_NODES * 4);
  int*   ccol   = (int*)  alloc((size_t)TOT_E * 4);
  float* cw     = (float*)alloc((size_t)TOT_E * 4);
  float* h      = (float*)alloc((size_t)N_NODES * H_DIM * 4);
  float* tmp    = (float*)alloc((size_t)N_NODES * H_DIM * 4);
  float* bufA   = (float*)alloc((size_t)N_NODES * H_DIM * 4);
  float* bufB   = (float*)alloc((size_t)N_NODES * H_DIM * 4);
  (void)ws_size; (void)in_sizes; (void)n_in; (void)out_size;

  dim3 b256(256);
  init_nodes_k<<<(N_NODES + 255) / 256, b256, 0, stream>>>(deg, cnt, N_NODES);
  edge_hist_k<<<(N_EDGES + 255) / 256, b256, 0, stream>>>(dst, ew, deg, cnt, N_EDGES);
  dinv_k<<<(N_NODES + 255) / 256, b256, 0, stream>>>(deg, N_NODES);
  scan_k<<<1, 1024, 0, stream>>>(cnt, rowp, cursor, N_NODES);
  scatter_k<<<(TOT_E + 255) / 256, b256, 0, stream>>>(src, dst, ew, deg, cursor,
                                                      ccol, cw, N_EDGES, N_NODES);

  // h = x @ W_in + b_in
  gemm_n128_k<<<(N_NODES + 63) / 64, b256, 0, stream>>>(x, W_in, b_in, h, N_NODES, F_IN);
  // out = b_out + h @ W_out[0:128]
  out_accum_k<<<(N_NODES + 127) / 128, b256, 0, stream>>>(h, W_out, b_out, out, N_NODES, 1);

  int k = 0;
  for (int j = 0; j < 4; ++j) {
    const float* cur = h;
    for (int s = 0; s <= j; ++s) {
      gemm_n128_k<<<(N_NODES + 63) / 64, b256, 0, stream>>>(
          cur, W_gcn + (size_t)k * H_DIM * H_DIM, nullptr, tmp, N_NODES, H_DIM);
      float* nxt = (cur == bufA) ? bufB : bufA;
      aggregate_k<<<(N_NODES + 3) / 4, b256, 0, stream>>>(
          rowp, ccol, cw, tmp, b_gcn + (size_t)k * H_DIM, nxt, N_NODES);
      cur = nxt;
      ++k;
    }
    // out += branch_result @ W_out[(j+1)*128 : (j+2)*128]
    out_accum_k<<<(N_NODES + 127) / 128, b256, 0, stream>>>(
        cur, W_out + (size_t)(j + 1) * H_DIM * C_OUT, b_out, out, N_NODES, 0);
  }
}

// Round 2
// 1136.426 us; speedup vs baseline: 1.3622x; 1.3622x over previous
//
#include <hip/hip_runtime.h>
#include <cstdint>
#include <cstddef>

#define N_NODES 50000
#define N_EDGES 800000
#define F_IN    512
#define H_DIM   128
#define C_OUT   40
#define TOT_E   (N_EDGES + N_NODES)

typedef __attribute__((ext_vector_type(8))) __bf16 bf16x8;
typedef __attribute__((ext_vector_type(4))) float f32x4;

__device__ __forceinline__ unsigned short bf16_rne(float f) {
  unsigned int u = __float_as_uint(f);
  u += 0x7fffu + ((u >> 16) & 1u);
  return (unsigned short)(u >> 16);
}
__device__ __forceinline__ float bf16_lo_f(unsigned int u) { return __uint_as_float(u << 16); }
__device__ __forceinline__ float bf16_hi_f(unsigned int u) { return __uint_as_float(u & 0xffff0000u); }

// ----------------------------- setup kernels -------------------------------

__global__ void init_nodes_k(float* deg, int* cnt, int n) {
  int i = blockIdx.x * blockDim.x + threadIdx.x;
  if (i < n) { deg[i] = 1.0f; cnt[i] = 1; }   // self-loop: weight 1, count 1
}

__global__ void edge_hist_k(const int* __restrict__ dst, const float* __restrict__ ew,
                            float* deg, int* cnt, int e) {
  int i = blockIdx.x * blockDim.x + threadIdx.x;
  if (i < e) {
    int d = dst[i];
    atomicAdd(&deg[d], ew[i]);
    atomicAdd(&cnt[d], 1);
  }
}

__global__ void dinv_k(float* deg, int n) {
  int i = blockIdx.x * blockDim.x + threadIdx.x;
  if (i < n) deg[i] = rsqrtf(deg[i]);   // deg >= 1 always (self-loop)
}

// ------------------------- parallel 3-phase scan ---------------------------

__global__ __launch_bounds__(256) void block_reduce_k(const int* __restrict__ cnt,
                                                      int* bsum, int n) {
  __shared__ int s[256];
  int t = threadIdx.x;
  int i = blockIdx.x * 256 + t;
  s[t] = (i < n) ? cnt[i] : 0;
  __syncthreads();
  for (int off = 128; off; off >>= 1) {
    if (t < off) s[t] += s[t + off];
    __syncthreads();
  }
  if (t == 0) bsum[blockIdx.x] = s[0];
}

// single block, exclusive-scan up to 256 block sums in place
__global__ __launch_bounds__(256) void scan_bsums_k(int* bsum, int nb) {
  __shared__ int s[256];
  int t = threadIdx.x;
  s[t] = (t < nb) ? bsum[t] : 0;
  __syncthreads();
  for (int off = 1; off < 256; off <<= 1) {
    int v = (t >= off) ? s[t - off] : 0;
    __syncthreads();
    s[t] += v;
    __syncthreads();
  }
  if (t < nb) bsum[t] = (t == 0) ? 0 : s[t - 1];
}

__global__ __launch_bounds__(256) void scan_write_k(const int* __restrict__ cnt,
                                                    const int* __restrict__ bsum,
                                                    int* row_ptr, int* cursor, int n) {
  __shared__ int s[256];
  int t = threadIdx.x;
  int i = blockIdx.x * 256 + t;
  int c = (i < n) ? cnt[i] : 0;
  s[t] = c;
  __syncthreads();
  for (int off = 1; off < 256; off <<= 1) {
    int v = (t >= off) ? s[t - off] : 0;
    __syncthreads();
    s[t] += v;
    __syncthreads();
  }
  int ex = bsum[blockIdx.x] + ((t == 0) ? 0 : s[t - 1]);
  if (i < n) { row_ptr[i] = ex; cursor[i] = ex; }
  if (i == n - 1) row_ptr[n] = ex + c;
}

// scatter edges (and self-loops) into CSR-by-dst, computing norm on the fly
__global__ void scatter_k(const int* __restrict__ src, const int* __restrict__ dst,
                          const float* __restrict__ ew, const float* __restrict__ dinv,
                          int* cursor, int* ccol, float* cw, int e, int n) {
  int i = blockIdx.x * blockDim.x + threadIdx.x;
  if (i < e) {
    int s = src[i], d = dst[i];
    float w = dinv[s] * ew[i] * dinv[d];
    int pos = atomicAdd(&cursor[d], 1);
    ccol[pos] = s;
    cw[pos] = w;
  } else if (i < e + n) {
    int v = i - e;
    float di = dinv[v];
    int pos = atomicAdd(&cursor[v], 1);
    ccol[pos] = v;
    cw[pos] = di * di;
  }
}

// ------------------- weight transpose+cast: Wt[n][k] = bf16(W[k][n]) -------
// W: [nmat][K][128] fp32 -> Wt: [nmat][128][K] bf16
__global__ void wcast_k(const float* __restrict__ W, unsigned short* __restrict__ Wt,
                        int K, int total) {
  int i = blockIdx.x * 256 + threadIdx.x;
  if (i >= total) return;
  int per = K * 128;
  int b = i / per;
  int rem = i - b * per;
  int k = rem >> 7, nn = rem & 127;
  Wt[(size_t)b * per + (size_t)nn * K + k] = bf16_rne(W[i]);
}

// --------------------- MFMA bf16 GEMM: C[M,128] = A[M,K] @ W[K,128] --------
// Block: 256 thr = 4 waves (2x2), tile 128x128, BK=64, mfma 16x16x32 bf16.
// LDS XOR-swizzle on 16B chunks: elem k of row m at ((k/8 ^ (m&7))*8 + k%8)
// -> staging writes and fragment ds_read_b128 are both 2-way (free).
// A fragment: A[m=lane&15][k=quad*8+j]; B frag: B[k=quad*8+j][n=lane&15];
// C/D: col=lane&15, row=quad*4+reg  (m89/m91-verified mappings).
template <int K, bool AFP32>
__global__ __launch_bounds__(256) void mfma_gemm_k(
    const void* __restrict__ Aptr, const unsigned short* __restrict__ Wt,
    const float* __restrict__ bias, unsigned short* __restrict__ C, int M) {
  constexpr int BK = 64;
  __shared__ __align__(16) unsigned short As[128][BK];
  __shared__ __align__(16) unsigned short Bs[128][BK];
  const int t = threadIdx.x;
  const int lane = t & 63;
  const int q = lane >> 4;
  const int l15 = lane & 15;
  const int w = t >> 6;
  const int wm = w >> 1, wn = w & 1;
  const int m0 = blockIdx.x * 128;

  f32x4 acc[4][4];
#pragma unroll
  for (int i = 0; i < 4; ++i)
#pragma unroll
    for (int j = 0; j < 4; ++j) acc[i][j] = (f32x4){0.f, 0.f, 0.f, 0.f};

  for (int k0 = 0; k0 < K; k0 += BK) {
    // ---- stage A (fused fp32->bf16 cast when AFP32) ----
    if constexpr (AFP32) {
      const float* A = (const float*)Aptr;
#pragma unroll
      for (int it = 0; it < 8; ++it) {
        int id = t + it * 256;            // 2048 float4 chunks (128 rows x 16)
        int r = id >> 4, f4 = id & 15;
        int gm = m0 + r; if (gm >= M) gm = M - 1;
        float4 a = *(const float4*)&A[(size_t)gm * K + k0 + (f4 << 2)];
        unsigned int u0 = (unsigned int)bf16_rne(a.x) | ((unsigned int)bf16_rne(a.y) << 16);
        unsigned int u1 = (unsigned int)bf16_rne(a.z) | ((unsigned int)bf16_rne(a.w) << 16);
        int kc = f4 >> 1, half = f4 & 1;
        *(uint2*)&As[r][((kc ^ (r & 7)) << 3) + (half << 2)] = make_uint2(u0, u1);
      }
    } else {
      const unsigned short* A = (const unsigned short*)Aptr;
#pragma unroll
      for (int it = 0; it < 4; ++it) {
        int id = t + it * 256;            // 1024 16B chunks (128 rows x 8)
        int r = id >> 3, kc = id & 7;
        int gm = m0 + r; if (gm >= M) gm = M - 1;
        uint4 v = *(const uint4*)&A[(size_t)gm * K + k0 + (kc << 3)];
        *(uint4*)&As[r][(kc ^ (r & 7)) << 3] = v;
      }
    }
    // ---- stage B from Wt[n][k] (row n contiguous in k) ----
#pragma unroll
    for (int it = 0; it < 4; ++it) {
      int id = t + it * 256;
      int nn = id >> 3, kc = id & 7;
      uint4 v = *(const uint4*)&Wt[(size_t)nn * K + k0 + (kc << 3)];
      *(uint4*)&Bs[nn][(kc ^ (nn & 7)) << 3] = v;
    }
    __syncthreads();
#pragma unroll
    for (int kk = 0; kk < 2; ++kk) {
      bf16x8 af[4], bfr[4];
#pragma unroll
      for (int i = 0; i < 4; ++i) {
        int m = (wm << 6) + (i << 4) + l15;
        int kc = (kk << 2) + q;
        af[i] = *(const bf16x8*)&As[m][(kc ^ (m & 7)) << 3];
        int nn = (wn << 6) + (i << 4) + l15;
        bfr[i] = *(const bf16x8*)&Bs[nn][(kc ^ (nn & 7)) << 3];
      }
#pragma unroll
      for (int i = 0; i < 4; ++i)
#pragma unroll
        for (int j = 0; j < 4; ++j)
          acc[i][j] = __builtin_amdgcn_mfma_f32_16x16x32_bf16(af[i], bfr[j], acc[i][j], 0, 0, 0);
    }
    __syncthreads();
  }
  // ---- epilogue: bf16 store (+ optional bias) ----
#pragma unroll
  for (int j = 0; j < 4; ++j) {
    int col = (wn << 6) + (j << 4) + l15;
    float bv = bias ? bias[col] : 0.0f;
#pragma unroll
    for (int i = 0; i < 4; ++i) {
      int rb = m0 + (wm << 6) + (i << 4) + (q << 2);
#pragma unroll
      for (int r = 0; r < 4; ++r) {
        int row = rb + r;
        if (row < M) C[(size_t)row * 128 + col] = bf16_rne(acc[i][j][r] + bv);
      }
    }
  }
}

// ------------------ sparse aggregation: out = CSR(hw) + bias ---------------
// one wave per node; lane holds a bf16 pair (4B) of the 256B row
__global__ __launch_bounds__(256) void aggregate_k(
    const int* __restrict__ row_ptr, const int* __restrict__ ccol,
    const float* __restrict__ cw, const unsigned int* __restrict__ hw,
    const float* __restrict__ bias, unsigned int* __restrict__ out, int n) {
  int lane = threadIdx.x & 63;
  int node = (blockIdx.x << 2) + (threadIdx.x >> 6);
  if (node >= n) return;
  int beg = row_ptr[node], end = row_ptr[node + 1];
  float ax = 0.f, ay = 0.f;
  int j = beg;
  for (; j + 1 < end; j += 2) {
    int c0 = ccol[j], c1 = ccol[j + 1];
    float w0 = cw[j], w1 = cw[j + 1];
    unsigned int u0 = hw[((size_t)c0 << 6) + lane];
    unsigned int u1 = hw[((size_t)c1 << 6) + lane];
    ax += w0 * bf16_lo_f(u0) + w1 * bf16_lo_f(u1);
    ay += w0 * bf16_hi_f(u0) + w1 * bf16_hi_f(u1);
  }
  if (j < end) {
    int c = ccol[j]; float w = cw[j];
    unsigned int u = hw[((size_t)c << 6) + lane];
    ax += w * bf16_lo_f(u); ay += w * bf16_hi_f(u);
  }
  float2 b = ((const float2*)bias)[lane];
  ax += b.x; ay += b.y;
  out[((size_t)node << 6) + lane] =
      (unsigned int)bf16_rne(ax) | ((unsigned int)bf16_rne(ay) << 16);
}

// ------------- output accumulation: out (+)= A[M,128]bf16 @ Wb[128,40] -----
__global__ __launch_bounds__(256) void out_accum_k(
    const unsigned short* __restrict__ A, const float* __restrict__ Wb,
    const float* __restrict__ bias, float* __restrict__ out,
    int M, int init) {
  __shared__ float As[32][129];
  __shared__ float Ws[32][40];
  const int t  = threadIdx.x;
  const int m0 = blockIdx.x * 128;
  const int ng = t >> 3;   // 0..31 row-group (4 rows)
  const int cg = t & 7;    // 0..7 col-group (5 cols)
  float acc[4][5];
#pragma unroll
  for (int i = 0; i < 4; ++i)
#pragma unroll
    for (int j = 0; j < 5; ++j) acc[i][j] = 0.0f;

  for (int k0 = 0; k0 < 128; k0 += 32) {
    // stage A 128x32 transposed, bf16 -> fp32
#pragma unroll
    for (int i = 0; i < 4; ++i) {
      int e4 = t + i * 256;        // 1024 chunks of 4 bf16
      int m  = e4 >> 3;            // 0..127
      int k4 = e4 & 7;             // 0..7
      int gm = m0 + m; if (gm >= M) gm = M - 1;
      uint2 u = *(const uint2*)&A[(size_t)gm * 128 + k0 + (k4 << 2)];
      As[(k4 << 2) + 0][m] = bf16_lo_f(u.x);
      As[(k4 << 2) + 1][m] = bf16_hi_f(u.x);
      As[(k4 << 2) + 2][m] = bf16_lo_f(u.y);
      As[(k4 << 2) + 3][m] = bf16_hi_f(u.y);
    }
    // stage W 32x40 = 1280 floats
#pragma unroll
    for (int i = 0; i < 5; ++i) {
      int e = t + i * 256;
      if (e < 1280) {
        int k = e / 40; int c = e - k * 40;
        Ws[k][c] = Wb[(size_t)(k0 + k) * 40 + c];
      }
    }
    __syncthreads();
#pragma unroll
    for (int k = 0; k < 32; ++k) {
      float av[4];
#pragma unroll
      for (int i = 0; i < 4; ++i) av[i] = As[k][(ng << 2) + i];
      float wv[5];
#pragma unroll
      for (int j = 0; j < 5; ++j) wv[j] = Ws[k][cg * 5 + j];
#pragma unroll
      for (int i = 0; i < 4; ++i)
#pragma unroll
        for (int j = 0; j < 5; ++j)
          acc[i][j] += av[i] * wv[j];
    }
    __syncthreads();
  }
#pragma unroll
  for (int i = 0; i < 4; ++i) {
    int gm = m0 + (ng << 2) + i;
    if (gm < M) {
#pragma unroll
      for (int j = 0; j < 5; ++j) {
        int c = cg * 5 + j;
        float v = acc[i][j];
        v += init ? bias[c] : out[(size_t)gm * 40 + c];
        out[(size_t)gm * 40 + c] = v;
      }
    }
  }
}

// ------------------------------- launcher ----------------------------------

extern "C" void kernel_launch(void* const* d_in, const int* in_sizes, int n_in,
                              void* d_out, int out_size, void* d_ws, size_t ws_size,
                              hipStream_t stream) {
  const float* x     = (const float*)d_in[0];
  const int*   eidx  = (const int*)  d_in[1];
  const float* ew    = (const float*)d_in[2];
  const float* W_in  = (const float*)d_in[3];
  const float* b_in  = (const float*)d_in[4];
  const float* W_gcn = (const float*)d_in[5];
  const float* b_gcn = (const float*)d_in[6];
  const float* W_out = (const float*)d_in[7];
  const float* b_out = (const float*)d_in[8];
  float* out = (float*)d_out;

  const int* src = eidx;             // edge_index[0]
  const int* dst = eidx + N_EDGES;   // edge_index[1]

  char* ws = (char*)d_ws;
  size_t off = 0;
  auto alloc = [&](size_t bytes) -> void* {
    void* p = ws + off;
    off += (bytes + 255) & ~(size_t)255;
    return p;
  };
  float* deg    = (float*)alloc((size_t)N_NODES * 4);     // becomes dinv
  int*   cnt    = (int*)  alloc((size_t)N_NODES * 4);
  int*   rowp   = (int*)  alloc((size_t)(N_NODES + 1) * 4);
  int*   cursor = (int*)  alloc((size_t)N_NODES * 4);
  int*   bsum   = (int*)  alloc((size_t)256 * 4);
  int*   ccol   = (int*)  alloc((size_t)TOT_E * 4);
  float* cw     = (float*)alloc((size_t)TOT_E * 4);
  unsigned short* Wt_in  = (unsigned short*)alloc((size_t)F_IN * H_DIM * 2);
  unsigned short* Wt_gcn = (unsigned short*)alloc((size_t)10 * H_DIM * H_DIM * 2);
  unsigned short* h_bf   = (unsigned short*)alloc((size_t)N_NODES * H_DIM * 2);
  unsigned short* tmp_bf = (unsigned short*)alloc((size_t)N_NODES * H_DIM * 2);
  unsigned short* bufA   = (unsigned short*)alloc((size_t)N_NODES * H_DIM * 2);
  unsigned short* bufB   = (unsigned short*)alloc((size_t)N_NODES * H_DIM * 2);
  (void)ws_size; (void)in_sizes; (void)n_in; (void)out_size;

  dim3 b256(256);
  const int NB = (N_NODES + 255) / 256;   // 196 scan blocks

  init_nodes_k<<<NB, b256, 0, stream>>>(deg, cnt, N_NODES);
  edge_hist_k<<<(N_EDGES + 255) / 256, b256, 0, stream>>>(dst, ew, deg, cnt, N_EDGES);
  dinv_k<<<NB, b256, 0, stream>>>(deg, N_NODES);
  block_reduce_k<<<NB, b256, 0, stream>>>(cnt, bsum, N_NODES);
  scan_bsums_k<<<1, b256, 0, stream>>>(bsum, NB);
  scan_write_k<<<NB, b256, 0, stream>>>(cnt, bsum, rowp, cursor, N_NODES);
  scatter_k<<<(TOT_E + 255) / 256, b256, 0, stream>>>(src, dst, ew, deg, cursor,
                                                      ccol, cw, N_EDGES, N_NODES);

  // weights -> bf16, transposed to [n][k]
  wcast_k<<<(F_IN * H_DIM + 255) / 256, b256, 0, stream>>>(W_in, Wt_in, F_IN, F_IN * H_DIM);
  wcast_k<<<(10 * H_DIM * H_DIM + 255) / 256, b256, 0, stream>>>(W_gcn, Wt_gcn, H_DIM,
                                                                 10 * H_DIM * H_DIM);

  const int GB = (N_NODES + 127) / 128;   // 391 gemm blocks

  // h = bf16(x @ W_in + b_in)   (fused fp32->bf16 cast of x in staging)
  mfma_gemm_k<F_IN, true><<<GB, b256, 0, stream>>>(x, Wt_in, b_in, h_bf, N_NODES);
  // out = b_out + h @ W_out[0:128]
  out_accum_k<<<GB, b256, 0, stream>>>(h_bf, W_out, b_out, out, N_NODES, 1);

  int k = 0;
  for (int j = 0; j < 4; ++j) {
    const unsigned short* cur = h_bf;
    for (int s = 0; s <= j; ++s) {
      mfma_gemm_k<H_DIM, false><<<GB, b256, 0, stream>>>(
          cur, Wt_gcn + (size_t)k * H_DIM * H_DIM, nullptr, tmp_bf, N_NODES);
      unsigned short* nxt = (cur == bufA) ? bufB : bufA;
      aggregate_k<<<(N_NODES + 3) / 4, b256, 0, stream>>>(
          rowp, ccol, cw, (const unsigned int*)tmp_bf, b_gcn + (size_t)k * H_DIM,
          (unsigned int*)nxt, N_NODES);
      cur = nxt;
      ++k;
    }
    // out += branch_result @ W_out[(j+1)*128 : (j+2)*128]
    out_accum_k<<<GB, b256, 0, stream>>>(
        cur, W_out + (size_t)(j + 1) * H_DIM * C_OUT, b_out, out, N_NODES, 0);
  }
}

// Round 3
// 757.052 us; speedup vs baseline: 2.0448x; 1.5011x over previous
//
#include <hip/hip_runtime.h>
#include <cstdint>
#include <cstddef>

#define N_NODES 50000
#define N_EDGES 800000
#define F_IN    512
#define H_DIM   128
#define C_OUT   40
#define TOT_E   (N_EDGES + N_NODES)

typedef __attribute__((ext_vector_type(8))) __bf16 bf16x8;
typedef __attribute__((ext_vector_type(4))) float f32x4;

__device__ __forceinline__ unsigned short bf16_rne(float f) {
  unsigned int u = __float_as_uint(f);
  u += 0x7fffu + ((u >> 16) & 1u);
  return (unsigned short)(u >> 16);
}
__device__ __forceinline__ float bf16_lo_f(unsigned int u) { return __uint_as_float(u << 16); }
__device__ __forceinline__ float bf16_hi_f(unsigned int u) { return __uint_as_float(u & 0xffff0000u); }

// ----------------------------- setup kernels -------------------------------
// Single u64 atomic per edge: bits [40..63] = count, bits [0..39] = fixed-point
// (2^-24) weighted degree. Returned old count = slot of this edge in its
// dst bucket -> CSR scatter needs no atomics.

__global__ void edge_pass1_k(const int* __restrict__ dst, const float* __restrict__ ew,
                             unsigned long long* __restrict__ acc,
                             int* __restrict__ pos, int e) {
  int i = blockIdx.x * blockDim.x + threadIdx.x;
  if (i < e) {
    int d = dst[i];
    unsigned long long v = (1ull << 40) |
        (unsigned long long)(ew[i] * 16777216.0f + 0.5f);
    unsigned long long old = atomicAdd(&acc[d], v);
    pos[i] = (int)(old >> 40);
  }
}

__global__ void node_pass_k(const unsigned long long* __restrict__ acc,
                            float* __restrict__ dinv, int* __restrict__ cnt, int n) {
  int i = blockIdx.x * blockDim.x + threadIdx.x;
  if (i < n) {
    unsigned long long a = acc[i];
    double dfix = (double)(a & 0xFFFFFFFFFFull);
    float deg = (float)(dfix * (1.0 / 16777216.0) + 1.0);   // +1 self-loop
    dinv[i] = rsqrtf(deg);
    cnt[i] = (int)(a >> 40) + 1;                            // +1 self-loop
  }
}

// ------------------------- parallel 3-phase scan ---------------------------

__global__ __launch_bounds__(256) void block_reduce_k(const int* __restrict__ cnt,
                                                      int* bsum, int n) {
  __shared__ int s[256];
  int t = threadIdx.x;
  int i = blockIdx.x * 256 + t;
  s[t] = (i < n) ? cnt[i] : 0;
  __syncthreads();
  for (int off = 128; off; off >>= 1) {
    if (t < off) s[t] += s[t + off];
    __syncthreads();
  }
  if (t == 0) bsum[blockIdx.x] = s[0];
}

__global__ __launch_bounds__(256) void scan_bsums_k(int* bsum, int nb) {
  __shared__ int s[256];
  int t = threadIdx.x;
  s[t] = (t < nb) ? bsum[t] : 0;
  __syncthreads();
  for (int off = 1; off < 256; off <<= 1) {
    int v = (t >= off) ? s[t - off] : 0;
    __syncthreads();
    s[t] += v;
    __syncthreads();
  }
  if (t < nb) bsum[t] = (t == 0) ? 0 : s[t - 1];
}

__global__ __launch_bounds__(256) void scan_write_k(const int* __restrict__ cnt,
                                                    const int* __restrict__ bsum,
                                                    int* row_ptr, int n) {
  __shared__ int s[256];
  int t = threadIdx.x;
  int i = blockIdx.x * 256 + t;
  int c = (i < n) ? cnt[i] : 0;
  s[t] = c;
  __syncthreads();
  for (int off = 1; off < 256; off <<= 1) {
    int v = (t >= off) ? s[t - off] : 0;
    __syncthreads();
    s[t] += v;
    __syncthreads();
  }
  int ex = bsum[blockIdx.x] + ((t == 0) ? 0 : s[t - 1]);
  if (i < n) row_ptr[i] = ex;
  if (i == n - 1) row_ptr[n] = ex + c;
}

// atomic-free CSR scatter: packed (col, weight-bits)
__global__ void scatter2_k(const int* __restrict__ src, const int* __restrict__ dst,
                           const float* __restrict__ ew, const int* __restrict__ pos,
                           const float* __restrict__ dinv, const int* __restrict__ rowp,
                           int2* __restrict__ csr, int e, int n) {
  int i = blockIdx.x * blockDim.x + threadIdx.x;
  if (i < e) {
    int s = src[i], d = dst[i];
    float w = dinv[s] * ew[i] * dinv[d];
    csr[rowp[d] + pos[i]] = make_int2(s, __float_as_int(w));
  } else if (i < e + n) {
    int v = i - e;
    float di = dinv[v];
    csr[rowp[v + 1] - 1] = make_int2(v, __float_as_int(di * di));  // self-loop last
  }
}

// ------------------- weight transpose+cast: Wt[n][k] = bf16(W[k][n]) -------
__global__ void wcast_k(const float* __restrict__ W, unsigned short* __restrict__ Wt,
                        int K, int total) {
  int i = blockIdx.x * 256 + threadIdx.x;
  if (i >= total) return;
  int per = K * 128;
  int b = i / per;
  int rem = i - b * per;
  int k = rem >> 7, nn = rem & 127;
  Wt[(size_t)b * per + (size_t)nn * K + k] = bf16_rne(W[i]);
}

// ------------- input MFMA GEMM: h = bf16(x[M,512] @ W_in + b_in) -----------
// 128x128 tile, BK=64, XOR-swizzled LDS (2-way = free). fp32->bf16 fused in
// A staging. Verified fragment mappings (m89/m91).
__global__ __launch_bounds__(256) void mfma_gemm_in_k(
    const float* __restrict__ A, const unsigned short* __restrict__ Wt,
    const float* __restrict__ bias, unsigned short* __restrict__ C, int M) {
  constexpr int K = F_IN, BK = 64;
  __shared__ __align__(16) unsigned short As[128][BK];
  __shared__ __align__(16) unsigned short Bs[128][BK];
  const int t = threadIdx.x;
  const int lane = t & 63;
  const int q = lane >> 4;
  const int l15 = lane & 15;
  const int w = t >> 6;
  const int wm = w >> 1, wn = w & 1;
  const int m0 = blockIdx.x * 128;

  f32x4 acc[4][4];
#pragma unroll
  for (int i = 0; i < 4; ++i)
#pragma unroll
    for (int j = 0; j < 4; ++j) acc[i][j] = (f32x4){0.f, 0.f, 0.f, 0.f};

  for (int k0 = 0; k0 < K; k0 += BK) {
#pragma unroll
    for (int it = 0; it < 8; ++it) {
      int id = t + it * 256;
      int r = id >> 4, f4 = id & 15;
      int gm = m0 + r; if (gm >= M) gm = M - 1;
      float4 a = *(const float4*)&A[(size_t)gm * K + k0 + (f4 << 2)];
      unsigned int u0 = (unsigned int)bf16_rne(a.x) | ((unsigned int)bf16_rne(a.y) << 16);
      unsigned int u1 = (unsigned int)bf16_rne(a.z) | ((unsigned int)bf16_rne(a.w) << 16);
      int kc = f4 >> 1, half = f4 & 1;
      *(uint2*)&As[r][((kc ^ (r & 7)) << 3) + (half << 2)] = make_uint2(u0, u1);
    }
#pragma unroll
    for (int it = 0; it < 4; ++it) {
      int id = t + it * 256;
      int nn = id >> 3, kc = id & 7;
      uint4 v = *(const uint4*)&Wt[(size_t)nn * K + k0 + (kc << 3)];
      *(uint4*)&Bs[nn][(kc ^ (nn & 7)) << 3] = v;
    }
    __syncthreads();
#pragma unroll
    for (int kk = 0; kk < 2; ++kk) {
      bf16x8 af[4], bfr[4];
#pragma unroll
      for (int i = 0; i < 4; ++i) {
        int m = (wm << 6) + (i << 4) + l15;
        int kc = (kk << 2) + q;
        af[i] = *(const bf16x8*)&As[m][(kc ^ (m & 7)) << 3];
        int nn = (wn << 6) + (i << 4) + l15;
        bfr[i] = *(const bf16x8*)&Bs[nn][(kc ^ (nn & 7)) << 3];
      }
#pragma unroll
      for (int i = 0; i < 4; ++i)
#pragma unroll
        for (int j = 0; j < 4; ++j)
          acc[i][j] = __builtin_amdgcn_mfma_f32_16x16x32_bf16(af[i], bfr[j], acc[i][j], 0, 0, 0);
    }
    __syncthreads();
  }
#pragma unroll
  for (int j = 0; j < 4; ++j) {
    int col = (wn << 6) + (j << 4) + l15;
    float bv = bias[col];
#pragma unroll
    for (int i = 0; i < 4; ++i) {
      int rb = m0 + (wm << 6) + (i << 4) + (q << 2);
#pragma unroll
      for (int r = 0; r < 4; ++r) {
        int row = rb + r;
        if (row < M) C[(size_t)row * 128 + col] = bf16_rne(acc[i][j][r] + bv);
      }
    }
  }
}

// --------- grouped MFMA GEMM (K=128): level of G independent convs ---------
// grid.y = group g. A column offset = acoStep ? (g+1)*128 : 0 (level input
// segments); weight = Wt_gcn[kidx[g]]; C written interleaved at col g*128.
__global__ __launch_bounds__(256) void mfma_gemm_g_k(
    const unsigned short* __restrict__ A, int lda, int acoStep,
    const unsigned short* __restrict__ Wt_all, int4 kidx,
    unsigned short* __restrict__ C, int ldc, int M) {
  constexpr int K = H_DIM, BK = 64;
  __shared__ __align__(16) unsigned short As[128][BK];
  __shared__ __align__(16) unsigned short Bs[128][BK];
  const int t = threadIdx.x;
  const int lane = t & 63;
  const int q = lane >> 4;
  const int l15 = lane & 15;
  const int w = t >> 6;
  const int wm = w >> 1, wn = w & 1;
  const int m0 = blockIdx.x * 128;
  const int g = blockIdx.y;
  const int aco = acoStep ? (g + 1) * H_DIM : 0;
  const int kw = (g == 0) ? kidx.x : (g == 1) ? kidx.y : (g == 2) ? kidx.z : kidx.w;
  const unsigned short* Wt = Wt_all + (size_t)kw * H_DIM * H_DIM;

  f32x4 acc[4][4];
#pragma unroll
  for (int i = 0; i < 4; ++i)
#pragma unroll
    for (int j = 0; j < 4; ++j) acc[i][j] = (f32x4){0.f, 0.f, 0.f, 0.f};

  for (int k0 = 0; k0 < K; k0 += BK) {
#pragma unroll
    for (int it = 0; it < 4; ++it) {
      int id = t + it * 256;
      int r = id >> 3, kc = id & 7;
      int gm = m0 + r; if (gm >= M) gm = M - 1;
      uint4 v = *(const uint4*)&A[(size_t)gm * lda + aco + k0 + (kc << 3)];
      *(uint4*)&As[r][(kc ^ (r & 7)) << 3] = v;
    }
#pragma unroll
    for (int it = 0; it < 4; ++it) {
      int id = t + it * 256;
      int nn = id >> 3, kc = id & 7;
      uint4 v = *(const uint4*)&Wt[(size_t)nn * K + k0 + (kc << 3)];
      *(uint4*)&Bs[nn][(kc ^ (nn & 7)) << 3] = v;
    }
    __syncthreads();
#pragma unroll
    for (int kk = 0; kk < 2; ++kk) {
      bf16x8 af[4], bfr[4];
#pragma unroll
      for (int i = 0; i < 4; ++i) {
        int m = (wm << 6) + (i << 4) + l15;
        int kc = (kk << 2) + q;
        af[i] = *(const bf16x8*)&As[m][(kc ^ (m & 7)) << 3];
        int nn = (wn << 6) + (i << 4) + l15;
        bfr[i] = *(const bf16x8*)&Bs[nn][(kc ^ (nn & 7)) << 3];
      }
#pragma unroll
      for (int i = 0; i < 4; ++i)
#pragma unroll
        for (int j = 0; j < 4; ++j)
          acc[i][j] = __builtin_amdgcn_mfma_f32_16x16x32_bf16(af[i], bfr[j], acc[i][j], 0, 0, 0);
    }
    __syncthreads();
  }
#pragma unroll
  for (int j = 0; j < 4; ++j) {
    int col = g * H_DIM + (wn << 6) + (j << 4) + l15;
#pragma unroll
    for (int i = 0; i < 4; ++i) {
      int rb = m0 + (wm << 6) + (i << 4) + (q << 2);
#pragma unroll
      for (int r = 0; r < 4; ++r) {
        int row = rb + r;
        if (row < M) C[(size_t)row * ldc + col] = bf16_rne(acc[i][j][r]);
      }
    }
  }
}

// ---------- batched aggregation: out[n, NSEG*128] = CSR(hw) + bias ---------
// one wave per node; lane handles 1 uint (2 bf16) per 128-col segment at
// row offset s*64+lane -> NSEG dense 256B gathers per edge, indices loaded once
template <int NSEG>
__global__ __launch_bounds__(256) void aggregate_lvl_k(
    const int* __restrict__ rowp, const int2* __restrict__ csr,
    const unsigned int* __restrict__ hw, const float* __restrict__ bgcn,
    const int4 kidx, unsigned int* __restrict__ outp, int n) {
  const int lane = threadIdx.x & 63;
  const int node = (blockIdx.x << 2) + (threadIdx.x >> 6);
  if (node >= n) return;
  const int RS = NSEG * 64;   // row stride in uints
  int beg = rowp[node], end = rowp[node + 1];
  float ax[NSEG], ay[NSEG];
#pragma unroll
  for (int s = 0; s < NSEG; ++s) { ax[s] = 0.f; ay[s] = 0.f; }
  int j = beg;
  for (; j + 1 < end; j += 2) {
    int2 e0 = csr[j], e1 = csr[j + 1];
    float w0 = __int_as_float(e0.y), w1 = __int_as_float(e1.y);
    const unsigned int* r0 = hw + (size_t)e0.x * RS + lane;
    const unsigned int* r1 = hw + (size_t)e1.x * RS + lane;
    unsigned int v0[NSEG], v1[NSEG];
#pragma unroll
    for (int s = 0; s < NSEG; ++s) { v0[s] = r0[s * 64]; v1[s] = r1[s * 64]; }
#pragma unroll
    for (int s = 0; s < NSEG; ++s) {
      ax[s] += w0 * bf16_lo_f(v0[s]) + w1 * bf16_lo_f(v1[s]);
      ay[s] += w0 * bf16_hi_f(v0[s]) + w1 * bf16_hi_f(v1[s]);
    }
  }
  if (j < end) {
    int2 e0 = csr[j];
    float w0 = __int_as_float(e0.y);
    const unsigned int* r0 = hw + (size_t)e0.x * RS + lane;
#pragma unroll
    for (int s = 0; s < NSEG; ++s) {
      unsigned int v = r0[s * 64];
      ax[s] += w0 * bf16_lo_f(v);
      ay[s] += w0 * bf16_hi_f(v);
    }
  }
#pragma unroll
  for (int s = 0; s < NSEG; ++s) {
    int kw = (s == 0) ? kidx.x : (s == 1) ? kidx.y : (s == 2) ? kidx.z : kidx.w;
    float2 b = *(const float2*)&bgcn[kw * 128 + lane * 2];
    float rx = ax[s] + b.x, ry = ay[s] + b.y;
    outp[(size_t)node * RS + s * 64 + lane] =
        (unsigned int)bf16_rne(rx) | ((unsigned int)bf16_rne(ry) << 16);
  }
}

// ------------- output accumulation: out (+)= A[M,128]bf16 @ Wb[128,40] -----
__global__ __launch_bounds__(256) void out_accum_k(
    const unsigned short* __restrict__ A, int lda, const float* __restrict__ Wb,
    const float* __restrict__ bias, float* __restrict__ out,
    int M, int init) {
  __shared__ float As[32][129];
  __shared__ float Ws[32][40];
  const int t  = threadIdx.x;
  const int m0 = blockIdx.x * 128;
  const int ng = t >> 3;
  const int cg = t & 7;
  float acc[4][5];
#pragma unroll
  for (int i = 0; i < 4; ++i)
#pragma unroll
    for (int j = 0; j < 5; ++j) acc[i][j] = 0.0f;

  for (int k0 = 0; k0 < 128; k0 += 32) {
#pragma unroll
    for (int i = 0; i < 4; ++i) {
      int e4 = t + i * 256;
      int m  = e4 >> 3;
      int k4 = e4 & 7;
      int gm = m0 + m; if (gm >= M) gm = M - 1;
      uint2 u = *(const uint2*)&A[(size_t)gm * lda + k0 + (k4 << 2)];
      As[(k4 << 2) + 0][m] = bf16_lo_f(u.x);
      As[(k4 << 2) + 1][m] = bf16_hi_f(u.x);
      As[(k4 << 2) + 2][m] = bf16_lo_f(u.y);
      As[(k4 << 2) + 3][m] = bf16_hi_f(u.y);
    }
#pragma unroll
    for (int i = 0; i < 5; ++i) {
      int e = t + i * 256;
      if (e < 1280) {
        int k = e / 40; int c = e - k * 40;
        Ws[k][c] = Wb[(size_t)(k0 + k) * 40 + c];
      }
    }
    __syncthreads();
#pragma unroll
    for (int k = 0; k < 32; ++k) {
      float av[4];
#pragma unroll
      for (int i = 0; i < 4; ++i) av[i] = As[k][(ng << 2) + i];
      float wv[5];
#pragma unroll
      for (int j = 0; j < 5; ++j) wv[j] = Ws[k][cg * 5 + j];
#pragma unroll
      for (int i = 0; i < 4; ++i)
#pragma unroll
        for (int j = 0; j < 5; ++j)
          acc[i][j] += av[i] * wv[j];
    }
    __syncthreads();
  }
#pragma unroll
  for (int i = 0; i < 4; ++i) {
    int gm = m0 + (ng << 2) + i;
    if (gm < M) {
#pragma unroll
      for (int j = 0; j < 5; ++j) {
        int c = cg * 5 + j;
        float v = acc[i][j];
        v += init ? bias[c] : out[(size_t)gm * 40 + c];
        out[(size_t)gm * 40 + c] = v;
      }
    }
  }
}

// ------------------------------- launcher ----------------------------------

extern "C" void kernel_launch(void* const* d_in, const int* in_sizes, int n_in,
                              void* d_out, int out_size, void* d_ws, size_t ws_size,
                              hipStream_t stream) {
  const float* x     = (const float*)d_in[0];
  const int*   eidx  = (const int*)  d_in[1];
  const float* ew    = (const float*)d_in[2];
  const float* W_in  = (const float*)d_in[3];
  const float* b_in  = (const float*)d_in[4];
  const float* W_gcn = (const float*)d_in[5];
  const float* b_gcn = (const float*)d_in[6];
  const float* W_out = (const float*)d_in[7];
  const float* b_out = (const float*)d_in[8];
  float* out = (float*)d_out;

  const int* src = eidx;
  const int* dst = eidx + N_EDGES;

  char* ws = (char*)d_ws;
  size_t off = 0;
  auto alloc = [&](size_t bytes) -> void* {
    void* p = ws + off;
    off += (bytes + 255) & ~(size_t)255;
    return p;
  };
  unsigned long long* acc = (unsigned long long*)alloc((size_t)N_NODES * 8);
  int*   pos    = (int*)  alloc((size_t)N_EDGES * 4);
  int*   cnt    = (int*)  alloc((size_t)N_NODES * 4);
  int*   rowp   = (int*)  alloc((size_t)(N_NODES + 1) * 4);
  float* dinv   = (float*)alloc((size_t)N_NODES * 4);
  int*   bsum   = (int*)  alloc((size_t)256 * 4);
  int2*  csr    = (int2*) alloc((size_t)TOT_E * 8);
  unsigned short* Wt_in  = (unsigned short*)alloc((size_t)F_IN * H_DIM * 2);
  unsigned short* Wt_gcn = (unsigned short*)alloc((size_t)10 * H_DIM * H_DIM * 2);
  unsigned short* h_bf   = (unsigned short*)alloc((size_t)N_NODES * H_DIM * 2);
  unsigned short* bufG   = (unsigned short*)alloc((size_t)N_NODES * 512 * 2);
  unsigned short* bufA   = (unsigned short*)alloc((size_t)N_NODES * 512 * 2);
  unsigned short* bufB   = (unsigned short*)alloc((size_t)N_NODES * 384 * 2);
  (void)ws_size; (void)in_sizes; (void)n_in; (void)out_size;

  dim3 b256(256);
  const int NB = (N_NODES + 255) / 256;
  const int GB = (N_NODES + 127) / 128;
  const int AB = (N_NODES + 3) / 4;

  hipMemsetAsync(acc, 0, (size_t)N_NODES * 8, stream);
  edge_pass1_k<<<(N_EDGES + 255) / 256, b256, 0, stream>>>(dst, ew, acc, pos, N_EDGES);
  node_pass_k<<<NB, b256, 0, stream>>>(acc, dinv, cnt, N_NODES);
  block_reduce_k<<<NB, b256, 0, stream>>>(cnt, bsum, N_NODES);
  scan_bsums_k<<<1, b256, 0, stream>>>(bsum, NB);
  scan_write_k<<<NB, b256, 0, stream>>>(cnt, bsum, rowp, N_NODES);
  scatter2_k<<<(TOT_E + 255) / 256, b256, 0, stream>>>(src, dst, ew, pos, dinv, rowp,
                                                       csr, N_EDGES, N_NODES);

  wcast_k<<<(F_IN * H_DIM + 255) / 256, b256, 0, stream>>>(W_in, Wt_in, F_IN, F_IN * H_DIM);
  wcast_k<<<(10 * H_DIM * H_DIM + 255) / 256, b256, 0, stream>>>(W_gcn, Wt_gcn, H_DIM,
                                                                 10 * H_DIM * H_DIM);

  // h = bf16(x @ W_in + b_in);  out = b_out + h @ W_out[0:128]
  mfma_gemm_in_k<<<GB, b256, 0, stream>>>(x, Wt_in, b_in, h_bf, N_NODES);
  out_accum_k<<<GB, b256, 0, stream>>>(h_bf, 128, W_out, b_out, out, N_NODES, 1);

  const unsigned int* hw;
  // ---- Level 1: convs {0,1,3,6} on h  -> bufA [N,512]
  mfma_gemm_g_k<<<dim3(GB, 4), b256, 0, stream>>>(h_bf, 128, 0, Wt_gcn,
                                                  make_int4(0, 1, 3, 6), bufG, 512, N_NODES);
  hw = (const unsigned int*)bufG;
  aggregate_lvl_k<4><<<AB, b256, 0, stream>>>(rowp, csr, hw, b_gcn,
                                              make_int4(0, 1, 3, 6),
                                              (unsigned int*)bufA, N_NODES);
  // branch1 final = bufA seg0
  out_accum_k<<<GB, b256, 0, stream>>>(bufA, 512, W_out + (size_t)1 * H_DIM * C_OUT,
                                       b_out, out, N_NODES, 0);

  // ---- Level 2: convs {2,4,7} on bufA segs {1,2,3} -> bufB [N,384]
  mfma_gemm_g_k<<<dim3(GB, 3), b256, 0, stream>>>(bufA, 512, 1, Wt_gcn,
                                                  make_int4(2, 4, 7, 0), bufG, 384, N_NODES);
  hw = (const unsigned int*)bufG;
  aggregate_lvl_k<3><<<AB, b256, 0, stream>>>(rowp, csr, hw, b_gcn,
                                              make_int4(2, 4, 7, 0),
                                              (unsigned int*)bufB, N_NODES);
  // branch2 final = bufB seg0
  out_accum_k<<<GB, b256, 0, stream>>>(bufB, 384, W_out + (size_t)2 * H_DIM * C_OUT,
                                       b_out, out, N_NODES, 0);

  // ---- Level 3: convs {5,8} on bufB segs {1,2} -> bufA [N,256]
  mfma_gemm_g_k<<<dim3(GB, 2), b256, 0, stream>>>(bufB, 384, 1, Wt_gcn,
                                                  make_int4(5, 8, 0, 0), bufG, 256, N_NODES);
  hw = (const unsigned int*)bufG;
  aggregate_lvl_k<2><<<AB, b256, 0, stream>>>(rowp, csr, hw, b_gcn,
                                              make_int4(5, 8, 0, 0),
                                              (unsigned int*)bufA, N_NODES);
  // branch3 final = bufA seg0
  out_accum_k<<<GB, b256, 0, stream>>>(bufA, 256, W_out + (size_t)3 * H_DIM * C_OUT,
                                       b_out, out, N_NODES, 0);

  // ---- Level 4: conv {9} on bufA seg {1} -> bufB [N,128]
  mfma_gemm_g_k<<<dim3(GB, 1), b256, 0, stream>>>(bufA, 256, 1, Wt_gcn,
                                                  make_int4(9, 0, 0, 0), bufG, 128, N_NODES);
  hw = (const unsigned int*)bufG;
  aggregate_lvl_k<1><<<AB, b256, 0, stream>>>(rowp, csr, hw, b_gcn,
                                              make_int4(9, 0, 0, 0),
                                              (unsigned int*)bufB, N_NODES);
  // branch4 final = bufB seg0
  out_accum_k<<<GB, b256, 0, stream>>>(bufB, 128, W_out + (size_t)4 * H_DIM * C_OUT,
                                       b_out, out, N_NODES, 0);
}

// Round 5
// 545.892 us; speedup vs baseline: 2.8357x; 1.3868x over previous
//
#include <hip/hip_runtime.h>
#include <cstdint>
#include <cstddef>

#define N_NODES 50000
#define N_EDGES 800000
#define F_IN    512
#define H_DIM   128
#define C_OUT   40
#define TOT_E   (N_EDGES + N_NODES)
#define KTOT    640             // h | u1 | u2 | u3 | u4
#define NPAD    48              // 40 cols padded to 3 MFMA tiles

typedef __attribute__((ext_vector_type(8))) __bf16 bf16x8;
typedef __attribute__((ext_vector_type(4))) float f32x4;

__device__ __forceinline__ unsigned short bf16_rne(float f) {
  unsigned int u = __float_as_uint(f);
  u += 0x7fffu + ((u >> 16) & 1u);
  return (unsigned short)(u >> 16);
}
__device__ __forceinline__ float bf16_lo_f(unsigned int u) { return __uint_as_float(u << 16); }
__device__ __forceinline__ float bf16_hi_f(unsigned int u) { return __uint_as_float(u & 0xffff0000u); }

// ----------------------------- setup kernels -------------------------------
// Single u64 atomic per edge: bits [40..63] = count, [0..39] = 2^-24 fixed-pt
// weighted degree. Returned old count = slot of edge in its dst bucket.

__global__ void edge_pass1_k(const int* __restrict__ dst, const float* __restrict__ ew,
                             unsigned long long* __restrict__ acc,
                             int* __restrict__ pos, int e) {
  int i = blockIdx.x * blockDim.x + threadIdx.x;
  if (i < e) {
    int d = dst[i];
    unsigned long long v = (1ull << 40) |
        (unsigned long long)(ew[i] * 16777216.0f + 0.5f);
    unsigned long long old = atomicAdd(&acc[d], v);
    pos[i] = (int)(old >> 40);
  }
}

__global__ void node_pass_k(const unsigned long long* __restrict__ acc,
                            float* __restrict__ dinv, int* __restrict__ cnt, int n) {
  int i = blockIdx.x * blockDim.x + threadIdx.x;
  if (i < n) {
    unsigned long long a = acc[i];
    double dfix = (double)(a & 0xFFFFFFFFFFull);
    float deg = (float)(dfix * (1.0 / 16777216.0) + 1.0);   // +1 self-loop
    dinv[i] = rsqrtf(deg);
    cnt[i] = (int)(a >> 40) + 1;                            // +1 self-loop
  }
}

__global__ __launch_bounds__(256) void block_reduce_k(const int* __restrict__ cnt,
                                                      int* bsum, int n) {
  __shared__ int s[256];
  int t = threadIdx.x;
  int i = blockIdx.x * 256 + t;
  s[t] = (i < n) ? cnt[i] : 0;
  __syncthreads();
  for (int off = 128; off; off >>= 1) {
    if (t < off) s[t] += s[t + off];
    __syncthreads();
  }
  if (t == 0) bsum[blockIdx.x] = s[0];
}

__global__ __launch_bounds__(256) void scan_bsums_k(int* bsum, int nb) {
  __shared__ int s[256];
  int t = threadIdx.x;
  s[t] = (t < nb) ? bsum[t] : 0;
  __syncthreads();
  for (int off = 1; off < 256; off <<= 1) {
    int v = (t >= off) ? s[t - off] : 0;
    __syncthreads();
    s[t] += v;
    __syncthreads();
  }
  if (t < nb) bsum[t] = (t == 0) ? 0 : s[t - 1];
}

__global__ __launch_bounds__(256) void scan_write_k(const int* __restrict__ cnt,
                                                    const int* __restrict__ bsum,
                                                    int* row_ptr, int n) {
  __shared__ int s[256];
  int t = threadIdx.x;
  int i = blockIdx.x * 256 + t;
  int c = (i < n) ? cnt[i] : 0;
  s[t] = c;
  __syncthreads();
  for (int off = 1; off < 256; off <<= 1) {
    int v = (t >= off) ? s[t - off] : 0;
    __syncthreads();
    s[t] += v;
    __syncthreads();
  }
  int ex = bsum[blockIdx.x] + ((t == 0) ? 0 : s[t - 1]);
  if (i < n) row_ptr[i] = ex;
  if (i == n - 1) row_ptr[n] = ex + c;
}

__global__ void scatter2_k(const int* __restrict__ src, const int* __restrict__ dst,
                           const float* __restrict__ ew, const int* __restrict__ pos,
                           const float* __restrict__ dinv, const int* __restrict__ rowp,
                           int2* __restrict__ csr, int e, int n) {
  int i = blockIdx.x * blockDim.x + threadIdx.x;
  if (i < e) {
    int s = src[i], d = dst[i];
    float w = dinv[s] * ew[i] * dinv[d];
    csr[rowp[d] + pos[i]] = make_int2(s, __float_as_int(w));
  } else if (i < e + n) {
    int v = i - e;
    float di = dinv[v];
    csr[rowp[v + 1] - 1] = make_int2(v, __float_as_int(di * di));  // self-loop last
  }
}

// ------------------- weight transpose+cast: Wt[n][k] = bf16(W[k][n]) -------
__global__ void wcast_k(const float* __restrict__ W, unsigned short* __restrict__ Wt,
                        int K, int total) {
  int i = blockIdx.x * 256 + threadIdx.x;
  if (i >= total) return;
  int per = K * 128;
  int b = i / per;
  int rem = i - b * per;
  int k = rem >> 7, nn = rem & 127;
  Wt[(size_t)b * per + (size_t)nn * K + k] = bf16_rne(W[i]);
}

// ---- weight-chain precompute: P slices [KTOT x 48] bf16 + rank-1 rows -----
// Block b handles branch j=b+1 (convs ks[b]).  S_j = Wo_j; repeatedly
// S <- W_k * S, harvesting bias row-vectors: rv[t] += b_k^T * S  (t = #mults
// done so far: 0->row_1, 1->row_d, 2->row_e, 3->row_f).
__global__ __launch_bounds__(256) void chains_k(
    const float* __restrict__ W_gcn, const float* __restrict__ b_gcn,
    const float* __restrict__ W_out, const float* __restrict__ b_out,
    unsigned short* __restrict__ Pbf, float* __restrict__ rv) {
  __shared__ float T0[128 * 40];
  __shared__ float T1[128 * 40];
  const int b = blockIdx.x;          // 0..3
  const int j = b + 1;
  const int ks_all[4][4] = {{0, -1, -1, -1}, {1, 2, -1, -1}, {3, 4, 5, -1}, {6, 7, 8, 9}};
  const int t = threadIdx.x;

  for (int idx = t; idx < 128 * 40; idx += 256) {
    int r = idx / 40, c = idx - r * 40;
    T0[idx] = W_out[(size_t)(j * 128 + r) * 40 + c];
  }
  __syncthreads();
  float* Tc = T0;
  float* Tn = T1;
  for (int step = 0; step < j; ++step) {
    int kw = ks_all[b][j - 1 - step];
    if (t < 40) {
      float s = 0.f;
      for (int r = 0; r < 128; ++r) s += b_gcn[kw * 128 + r] * Tc[r * 40 + t];
      atomicAdd(&rv[step * 40 + t], s);
    }
    // Tn = W_gcn[kw] * Tc
    const float* W = W_gcn + (size_t)kw * 128 * 128;
    {
      int r = t >> 1, c0 = (t & 1) * 20;
      float a20[20];
#pragma unroll
      for (int c = 0; c < 20; ++c) a20[c] = 0.f;
      for (int k = 0; k < 128; k += 4) {
        float4 wv = *(const float4*)&W[(size_t)r * 128 + k];
#pragma unroll
        for (int kk = 0; kk < 4; ++kk) {
          float wk = (&wv.x)[kk];
          const float* Trow = &Tc[(k + kk) * 40 + c0];
#pragma unroll
          for (int c = 0; c < 20; ++c) a20[c] += wk * Trow[c];
        }
      }
#pragma unroll
      for (int c = 0; c < 20; ++c) Tn[r * 40 + c0 + c] = a20[c];
    }
    __syncthreads();
    float* tmp = Tc; Tc = Tn; Tn = tmp;
  }
  // write P slice for u_j: k rows [j*128, j*128+128), n-major bf16, pad n>=40
  for (int idx = t; idx < NPAD * 128; idx += 256) {
    int n = idx >> 7, r = idx & 127;
    float v = (n < 40) ? Tc[r * 40 + n] : 0.f;
    Pbf[(size_t)n * KTOT + j * 128 + r] = bf16_rne(v);
  }
  if (b == 0) {
    for (int idx = t; idx < NPAD * 128; idx += 256) {
      int n = idx >> 7, r = idx & 127;
      float v = (n < 40) ? W_out[(size_t)r * 40 + n] : 0.f;
      Pbf[(size_t)n * KTOT + r] = bf16_rne(v);
    }
    if (t < 40) atomicAdd(&rv[t], b_out[t]);   // row_1 += b_out
  }
}

// ------------- input MFMA GEMM: U[:,0:128] = bf16(x @ W_in + b_in) ---------
__global__ __launch_bounds__(256) void mfma_gemm_in_k(
    const float* __restrict__ A, const unsigned short* __restrict__ Wt,
    const float* __restrict__ bias, unsigned short* __restrict__ C, int M) {
  constexpr int K = F_IN, BK = 64;
  __shared__ __align__(16) unsigned short As[128][BK];
  __shared__ __align__(16) unsigned short Bs[128][BK];
  const int t = threadIdx.x;
  const int lane = t & 63;
  const int q = lane >> 4;
  const int l15 = lane & 15;
  const int w = t >> 6;
  const int wm = w >> 1, wn = w & 1;
  const int m0 = blockIdx.x * 128;

  f32x4 acc[4][4];
#pragma unroll
  for (int i = 0; i < 4; ++i)
#pragma unroll
    for (int j = 0; j < 4; ++j) acc[i][j] = (f32x4){0.f, 0.f, 0.f, 0.f};

  for (int k0 = 0; k0 < K; k0 += BK) {
#pragma unroll
    for (int it = 0; it < 8; ++it) {
      int id = t + it * 256;
      int r = id >> 4, f4 = id & 15;
      int gm = m0 + r; if (gm >= M) gm = M - 1;
      float4 a = *(const float4*)&A[(size_t)gm * K + k0 + (f4 << 2)];
      unsigned int u0 = (unsigned int)bf16_rne(a.x) | ((unsigned int)bf16_rne(a.y) << 16);
      unsigned int u1 = (unsigned int)bf16_rne(a.z) | ((unsigned int)bf16_rne(a.w) << 16);
      int kc = f4 >> 1, half = f4 & 1;
      *(uint2*)&As[r][((kc ^ (r & 7)) << 3) + (half << 2)] = make_uint2(u0, u1);
    }
#pragma unroll
    for (int it = 0; it < 4; ++it) {
      int id = t + it * 256;
      int nn = id >> 3, kc = id & 7;
      uint4 v = *(const uint4*)&Wt[(size_t)nn * K + k0 + (kc << 3)];
      *(uint4*)&Bs[nn][(kc ^ (nn & 7)) << 3] = v;
    }
    __syncthreads();
#pragma unroll
    for (int kk = 0; kk < 2; ++kk) {
      bf16x8 af[4], bfr[4];
#pragma unroll
      for (int i = 0; i < 4; ++i) {
        int m = (wm << 6) + (i << 4) + l15;
        int kc = (kk << 2) + q;
        af[i] = *(const bf16x8*)&As[m][(kc ^ (m & 7)) << 3];
        int nn = (wn << 6) + (i << 4) + l15;
        bfr[i] = *(const bf16x8*)&Bs[nn][(kc ^ (nn & 7)) << 3];
      }
#pragma unroll
      for (int i = 0; i < 4; ++i)
#pragma unroll
        for (int j = 0; j < 4; ++j)
          acc[i][j] = __builtin_amdgcn_mfma_f32_16x16x32_bf16(af[i], bfr[j], acc[i][j], 0, 0, 0);
    }
    __syncthreads();
  }
#pragma unroll
  for (int j = 0; j < 4; ++j) {
    int col = (wn << 6) + (j << 4) + l15;
    float bv = bias[col];
#pragma unroll
    for (int i = 0; i < 4; ++i) {
      int rb = m0 + (wm << 6) + (i << 4) + (q << 2);
#pragma unroll
      for (int r = 0; r < 4; ++r) {
        int row = rb + r;
        if (row < M) C[(size_t)row * KTOT + col] = bf16_rne(acc[i][j][r] + bv);
      }
    }
  }
}

// ------------- aggregation: U[:,out] = A * U[:,in]; scalar chain -----------
// SMODE 0: none; 1: sout = sum w (d = A*1); 2: sout = sum w*sprev[src]
template <int SMODE>
__global__ __launch_bounds__(256) void agg_k(
    const int* __restrict__ rowp, const int2* __restrict__ csr,
    unsigned int* __restrict__ U32, int co_in, int co_out,
    const float* __restrict__ sprev, float* __restrict__ sout, int n) {
  const int lane = threadIdx.x & 63;
  const int node = (blockIdx.x << 2) + (threadIdx.x >> 6);
  if (node >= n) return;
  const int RS = KTOT / 2;   // 320 uints per row
  int beg = rowp[node], end = rowp[node + 1];
  float ax = 0.f, ay = 0.f, sacc = 0.f;
  const unsigned int* in = U32 + co_in + lane;
  int j = beg;
  for (; j + 1 < end; j += 2) {
    int2 e0 = csr[j], e1 = csr[j + 1];
    float w0 = __int_as_float(e0.y), w1 = __int_as_float(e1.y);
    unsigned int v0 = in[(size_t)e0.x * RS];
    unsigned int v1 = in[(size_t)e1.x * RS];
    ax += w0 * bf16_lo_f(v0) + w1 * bf16_lo_f(v1);
    ay += w0 * bf16_hi_f(v0) + w1 * bf16_hi_f(v1);
    if (SMODE == 1) sacc += w0 + w1;
    if (SMODE == 2) sacc += w0 * sprev[e0.x] + w1 * sprev[e1.x];
  }
  if (j < end) {
    int2 e0 = csr[j];
    float w0 = __int_as_float(e0.y);
    unsigned int v0 = in[(size_t)e0.x * RS];
    ax += w0 * bf16_lo_f(v0);
    ay += w0 * bf16_hi_f(v0);
    if (SMODE == 1) sacc += w0;
    if (SMODE == 2) sacc += w0 * sprev[e0.x];
  }
  U32[(size_t)node * RS + co_out + lane] =
      (unsigned int)bf16_rne(ax) | ((unsigned int)bf16_rne(ay) << 16);
  if (SMODE != 0 && lane == 0) sout[node] = sacc;
}

// ------ final fused GEMM: out = U[M,640] @ P[640,40] + rank-1 terms --------
__global__ __launch_bounds__(256) void final_gemm_k(
    const unsigned short* __restrict__ U, const unsigned short* __restrict__ Pbf,
    const float* __restrict__ dvec, const float* __restrict__ evec,
    const float* __restrict__ fvec, const float* __restrict__ rv,
    float* __restrict__ out, int M) {
  constexpr int K = KTOT, BK = 64;
  __shared__ __align__(16) unsigned short As[128][BK];
  __shared__ __align__(16) unsigned short Bs[NPAD][BK];
  const int t = threadIdx.x;
  const int lane = t & 63;
  const int q = lane >> 4;
  const int l15 = lane & 15;
  const int w = t >> 6;
  const int m0 = blockIdx.x * 128;

  f32x4 acc[2][3];
#pragma unroll
  for (int i = 0; i < 2; ++i)
#pragma unroll
    for (int j = 0; j < 3; ++j) acc[i][j] = (f32x4){0.f, 0.f, 0.f, 0.f};

  for (int k0 = 0; k0 < K; k0 += BK) {
#pragma unroll
    for (int it = 0; it < 4; ++it) {
      int id = t + it * 256;
      int r = id >> 3, kc = id & 7;
      int gm = m0 + r; if (gm >= M) gm = M - 1;
      uint4 v = *(const uint4*)&U[(size_t)gm * K + k0 + (kc << 3)];
      *(uint4*)&As[r][(kc ^ (r & 7)) << 3] = v;
    }
    // FIX (round 4 bug): NPAD*8 = 384 chunks but only 256 threads — must loop.
    for (int id = t; id < NPAD * 8; id += 256) {
      int nn = id >> 3, kc = id & 7;
      uint4 v = *(const uint4*)&Pbf[(size_t)nn * K + k0 + (kc << 3)];
      *(uint4*)&Bs[nn][(kc ^ (nn & 7)) << 3] = v;
    }
    __syncthreads();
#pragma unroll
    for (int kk = 0; kk < 2; ++kk) {
      bf16x8 af[2], bfr[3];
#pragma unroll
      for (int i = 0; i < 2; ++i) {
        int m = (w << 5) + (i << 4) + l15;
        int kc = (kk << 2) + q;
        af[i] = *(const bf16x8*)&As[m][(kc ^ (m & 7)) << 3];
      }
#pragma unroll
      for (int j = 0; j < 3; ++j) {
        int nn = (j << 4) + l15;
        int kc = (kk << 2) + q;
        bfr[j] = *(const bf16x8*)&Bs[nn][(kc ^ (nn & 7)) << 3];
      }
#pragma unroll
      for (int i = 0; i < 2; ++i)
#pragma unroll
        for (int j = 0; j < 3; ++j)
          acc[i][j] = __builtin_amdgcn_mfma_f32_16x16x32_bf16(af[i], bfr[j], acc[i][j], 0, 0, 0);
    }
    __syncthreads();
  }
  // epilogue: + d*rv1 + e*rv2 + f*rv3 + rv0, fp32 out[M,40]
#pragma unroll
  for (int j = 0; j < 3; ++j) {
    int col = (j << 4) + l15;
    if (col >= C_OUT) continue;
    float r1 = rv[0 * 40 + col], rd = rv[1 * 40 + col];
    float re = rv[2 * 40 + col], rf = rv[3 * 40 + col];
#pragma unroll
    for (int i = 0; i < 2; ++i) {
      int rb = m0 + (w << 5) + (i << 4) + (q << 2);
#pragma unroll
      for (int r = 0; r < 4; ++r) {
        int row = rb + r;
        if (row < M) {
          float v = acc[i][j][r] + r1 +
                    dvec[row] * rd + evec[row] * re + fvec[row] * rf;
          out[(size_t)row * C_OUT + col] = v;
        }
      }
    }
  }
}

// ------------------------------- launcher ----------------------------------

extern "C" void kernel_launch(void* const* d_in, const int* in_sizes, int n_in,
                              void* d_out, int out_size, void* d_ws, size_t ws_size,
                              hipStream_t stream) {
  const float* x     = (const float*)d_in[0];
  const int*   eidx  = (const int*)  d_in[1];
  const float* ew    = (const float*)d_in[2];
  const float* W_in  = (const float*)d_in[3];
  const float* b_in  = (const float*)d_in[4];
  const float* W_gcn = (const float*)d_in[5];
  const float* b_gcn = (const float*)d_in[6];
  const float* W_out = (const float*)d_in[7];
  const float* b_out = (const float*)d_in[8];
  float* out = (float*)d_out;

  const int* src = eidx;
  const int* dst = eidx + N_EDGES;

  char* ws = (char*)d_ws;
  size_t off = 0;
  auto alloc = [&](size_t bytes) -> void* {
    void* p = ws + off;
    off += (bytes + 255) & ~(size_t)255;
    return p;
  };
  unsigned long long* acc = (unsigned long long*)alloc((size_t)N_NODES * 8);
  int*   pos    = (int*)  alloc((size_t)N_EDGES * 4);
  int*   cnt    = (int*)  alloc((size_t)N_NODES * 4);
  int*   rowp   = (int*)  alloc((size_t)(N_NODES + 1) * 4);
  float* dinv   = (float*)alloc((size_t)N_NODES * 4);
  int*   bsum   = (int*)  alloc((size_t)256 * 4);
  int2*  csr    = (int2*) alloc((size_t)TOT_E * 8);
  unsigned short* Wt_in = (unsigned short*)alloc((size_t)F_IN * H_DIM * 2);
  unsigned short* Pbf   = (unsigned short*)alloc((size_t)NPAD * KTOT * 2);
  unsigned short* U     = (unsigned short*)alloc((size_t)N_NODES * KTOT * 2);
  float* dvec   = (float*)alloc((size_t)N_NODES * 4);
  float* evec   = (float*)alloc((size_t)N_NODES * 4);
  float* fvec   = (float*)alloc((size_t)N_NODES * 4);
  float* rv     = (float*)alloc((size_t)4 * 40 * 4);
  (void)ws_size; (void)in_sizes; (void)n_in; (void)out_size;

  dim3 b256(256);
  const int NB = (N_NODES + 255) / 256;
  const int GB = (N_NODES + 127) / 128;
  const int AB = (N_NODES + 3) / 4;
  unsigned int* U32 = (unsigned int*)U;

  hipMemsetAsync(acc, 0, (size_t)N_NODES * 8, stream);
  hipMemsetAsync(rv, 0, (size_t)4 * 40 * 4, stream);

  edge_pass1_k<<<(N_EDGES + 255) / 256, b256, 0, stream>>>(dst, ew, acc, pos, N_EDGES);
  node_pass_k<<<NB, b256, 0, stream>>>(acc, dinv, cnt, N_NODES);
  block_reduce_k<<<NB, b256, 0, stream>>>(cnt, bsum, N_NODES);
  scan_bsums_k<<<1, b256, 0, stream>>>(bsum, NB);
  scan_write_k<<<NB, b256, 0, stream>>>(cnt, bsum, rowp, N_NODES);
  scatter2_k<<<(TOT_E + 255) / 256, b256, 0, stream>>>(src, dst, ew, pos, dinv, rowp,
                                                       csr, N_EDGES, N_NODES);

  wcast_k<<<(F_IN * H_DIM + 255) / 256, b256, 0, stream>>>(W_in, Wt_in, F_IN, F_IN * H_DIM);
  chains_k<<<4, b256, 0, stream>>>(W_gcn, b_gcn, W_out, b_out, Pbf, rv);

  // U[:,0:128] = bf16(x @ W_in + b_in)
  mfma_gemm_in_k<<<GB, b256, 0, stream>>>(x, Wt_in, b_in, U, N_NODES);

  // u-chain: u_{p} = A * u_{p-1}; scalar chain d = A*1, e = A*d, f = A*e
  agg_k<1><<<AB, b256, 0, stream>>>(rowp, csr, U32, 0,   64,  nullptr, dvec, N_NODES);
  agg_k<2><<<AB, b256, 0, stream>>>(rowp, csr, U32, 64,  128, dvec,    evec, N_NODES);
  agg_k<2><<<AB, b256, 0, stream>>>(rowp, csr, U32, 128, 192, evec,    fvec, N_NODES);
  agg_k<0><<<AB, b256, 0, stream>>>(rowp, csr, U32, 192, 256, nullptr, nullptr, N_NODES);

  final_gemm_k<<<GB, b256, 0, stream>>>(U, Pbf, dvec, evec, fvec, rv, out, N_NODES);
}

// Round 6
// 524.691 us; speedup vs baseline: 2.9503x; 1.0404x over previous
//
#include <hip/hip_runtime.h>
#include <cstdint>
#include <cstddef>

#define N_NODES 50000
#define N_EDGES 800000
#define F_IN    512
#define H_DIM   128
#define C_OUT   40
#define TOT_E   (N_EDGES + N_NODES)
#define KTOT    640             // h | u1 | u2 | u3 | u4
#define NPAD    48              // 40 cols padded to 3 MFMA tiles

typedef __attribute__((ext_vector_type(8))) __bf16 bf16x8;
typedef __attribute__((ext_vector_type(4))) float f32x4;

__device__ __forceinline__ unsigned short bf16_rne(float f) {
  unsigned int u = __float_as_uint(f);
  u += 0x7fffu + ((u >> 16) & 1u);
  return (unsigned short)(u >> 16);
}
__device__ __forceinline__ float bf16_lo_f(unsigned int u) { return __uint_as_float(u << 16); }
__device__ __forceinline__ float bf16_hi_f(unsigned int u) { return __uint_as_float(u & 0xffff0000u); }

// ----------------------------- setup kernels -------------------------------
// Single u64 atomic per edge: bits [40..63] = count, [0..39] = 2^-24 fixed-pt
// weighted degree. Returned old count = slot of edge in its dst bucket.

__global__ void edge_pass1_k(const int* __restrict__ dst, const float* __restrict__ ew,
                             unsigned long long* __restrict__ acc,
                             int* __restrict__ pos, int e) {
  int i = blockIdx.x * blockDim.x + threadIdx.x;
  if (i < e) {
    int d = dst[i];
    unsigned long long v = (1ull << 40) |
        (unsigned long long)(ew[i] * 16777216.0f + 0.5f);
    unsigned long long old = atomicAdd(&acc[d], v);
    pos[i] = (int)(old >> 40);
  }
}

__global__ void node_pass_k(const unsigned long long* __restrict__ acc,
                            float* __restrict__ dinv, int* __restrict__ cnt, int n) {
  int i = blockIdx.x * blockDim.x + threadIdx.x;
  if (i < n) {
    unsigned long long a = acc[i];
    double dfix = (double)(a & 0xFFFFFFFFFFull);
    float deg = (float)(dfix * (1.0 / 16777216.0) + 1.0);   // +1 self-loop
    dinv[i] = rsqrtf(deg);
    cnt[i] = (int)(a >> 40) + 1;                            // +1 self-loop
  }
}

__global__ __launch_bounds__(256) void block_reduce_k(const int* __restrict__ cnt,
                                                      int* bsum, int n) {
  __shared__ int s[256];
  int t = threadIdx.x;
  int i = blockIdx.x * 256 + t;
  s[t] = (i < n) ? cnt[i] : 0;
  __syncthreads();
  for (int off = 128; off; off >>= 1) {
    if (t < off) s[t] += s[t + off];
    __syncthreads();
  }
  if (t == 0) bsum[blockIdx.x] = s[0];
}

__global__ __launch_bounds__(256) void scan_bsums_k(int* bsum, int nb) {
  __shared__ int s[256];
  int t = threadIdx.x;
  s[t] = (t < nb) ? bsum[t] : 0;
  __syncthreads();
  for (int off = 1; off < 256; off <<= 1) {
    int v = (t >= off) ? s[t - off] : 0;
    __syncthreads();
    s[t] += v;
    __syncthreads();
  }
  if (t < nb) bsum[t] = (t == 0) ? 0 : s[t - 1];
}

__global__ __launch_bounds__(256) void scan_write_k(const int* __restrict__ cnt,
                                                    const int* __restrict__ bsum,
                                                    int* row_ptr, int n) {
  __shared__ int s[256];
  int t = threadIdx.x;
  int i = blockIdx.x * 256 + t;
  int c = (i < n) ? cnt[i] : 0;
  s[t] = c;
  __syncthreads();
  for (int off = 1; off < 256; off <<= 1) {
    int v = (t >= off) ? s[t - off] : 0;
    __syncthreads();
    s[t] += v;
    __syncthreads();
  }
  int ex = bsum[blockIdx.x] + ((t == 0) ? 0 : s[t - 1]);
  if (i < n) row_ptr[i] = ex;
  if (i == n - 1) row_ptr[n] = ex + c;
}

__global__ void scatter2_k(const int* __restrict__ src, const int* __restrict__ dst,
                           const float* __restrict__ ew, const int* __restrict__ pos,
                           const float* __restrict__ dinv, const int* __restrict__ rowp,
                           int2* __restrict__ csr, int e, int n) {
  int i = blockIdx.x * blockDim.x + threadIdx.x;
  if (i < e) {
    int s = src[i], d = dst[i];
    float w = dinv[s] * ew[i] * dinv[d];
    csr[rowp[d] + pos[i]] = make_int2(s, __float_as_int(w));
  } else if (i < e + n) {
    int v = i - e;
    float di = dinv[v];
    csr[rowp[v + 1] - 1] = make_int2(v, __float_as_int(di * di));  // self-loop last
  }
}

// ------------------- weight transpose+cast: Wt[n][k] = bf16(W[k][n]) -------
__global__ void wcast_k(const float* __restrict__ W, unsigned short* __restrict__ Wt,
                        int K, int total) {
  int i = blockIdx.x * 256 + threadIdx.x;
  if (i >= total) return;
  int per = K * 128;
  int b = i / per;
  int rem = i - b * per;
  int k = rem >> 7, nn = rem & 127;
  Wt[(size_t)b * per + (size_t)nn * K + k] = bf16_rne(W[i]);
}

// ---- weight-chain precompute: P slices [KTOT x 48] bf16 + rank-1 rows -----
// Column-parallel rewrite: grid (10, 4). blockIdx.y = branch b (j=b+1),
// blockIdx.x = column group (4 of the 40 output cols). Each block evolves a
// 128x4 slice S <- W_k * S; chains act on columns independently.
// rv[t][col] += b_k^T * S harvested per step via wave-shuffle reduce.
__global__ __launch_bounds__(256) void chains_k(
    const float* __restrict__ W_gcn, const float* __restrict__ b_gcn,
    const float* __restrict__ W_out, const float* __restrict__ b_out,
    unsigned short* __restrict__ Pbf, float* __restrict__ rv) {
  __shared__ float T0[128 * 4];
  __shared__ float T1[128 * 4];
  const int b = blockIdx.y;          // 0..3
  const int j = b + 1;
  const int c0 = blockIdx.x * 4;     // col group base
  const int ks_all[4][4] = {{0, -1, -1, -1}, {1, 2, -1, -1}, {3, 4, 5, -1}, {6, 7, 8, 9}};
  const int t = threadIdx.x;
  const int lane = t & 63;
  const int wv = t >> 6;             // wave 0..3

  for (int idx = t; idx < 512; idx += 256) {
    int r = idx >> 2, c = idx & 3;
    T0[idx] = W_out[(size_t)(j * 128 + r) * 40 + c0 + c];
  }
  __syncthreads();
  float* Tc = T0;
  float* Tn = T1;
  for (int step = 0; step < j; ++step) {
    int kw = ks_all[b][j - 1 - step];
    // rv[step][c0+wv] += b_gcn[kw]^T * Tc[:, wv]  (wave wv owns col wv)
    {
      float s = b_gcn[kw * 128 + lane] * Tc[lane * 4 + wv] +
                b_gcn[kw * 128 + 64 + lane] * Tc[(64 + lane) * 4 + wv];
      for (int o = 32; o; o >>= 1) s += __shfl_down(s, o);
      if (lane == 0) atomicAdd(&rv[step * 40 + c0 + wv], s);
    }
    // Tn = W_gcn[kw] @ Tc : thread handles row r, cols {ch, ch+1}
    const float* W = W_gcn + (size_t)kw * 128 * 128;
    int r = t & 127;
    int ch = (t >> 7) << 1;          // 0 or 2
    float a0 = 0.f, a1 = 0.f;
    for (int k = 0; k < 128; k += 4) {
      float4 w4 = *(const float4*)&W[(size_t)r * 128 + k];
      a0 += w4.x * Tc[(k + 0) * 4 + ch] + w4.y * Tc[(k + 1) * 4 + ch] +
            w4.z * Tc[(k + 2) * 4 + ch] + w4.w * Tc[(k + 3) * 4 + ch];
      a1 += w4.x * Tc[(k + 0) * 4 + ch + 1] + w4.y * Tc[(k + 1) * 4 + ch + 1] +
            w4.z * Tc[(k + 2) * 4 + ch + 1] + w4.w * Tc[(k + 3) * 4 + ch + 1];
    }
    Tn[r * 4 + ch] = a0;
    Tn[r * 4 + ch + 1] = a1;
    __syncthreads();
    float* tmp = Tc; Tc = Tn; Tn = tmp;
  }
  // P slice for u_j: rows [j*128, j*128+128), cols c0..c0+3 (n-major)
  for (int idx = t; idx < 512; idx += 256) {
    int r = idx >> 2, c = idx & 3;
    Pbf[(size_t)(c0 + c) * KTOT + j * 128 + r] = bf16_rne(Tc[idx]);
  }
  if (b == 0) {
    // h slice: P[n][0:128] = W_out rows 0..127 (this block's 4 cols)
    for (int idx = t; idx < 512; idx += 256) {
      int r = idx >> 2, c = idx & 3;
      Pbf[(size_t)(c0 + c) * KTOT + r] = bf16_rne(W_out[(size_t)r * 40 + c0 + c]);
    }
    if (blockIdx.x == 0 && t < 40) atomicAdd(&rv[t], b_out[t]);   // row_1 += b_out
  }
}

// ------------- input MFMA GEMM: U[:,0:128] = bf16(x @ W_in + b_in) ---------
// 64x128 tile (782 blocks -> ~3 blocks/CU; round-5 128-tile was grid-limited
// at 14% occupancy). BK=64, XOR-swizzled LDS, fused fp32->bf16 A staging.
__global__ __launch_bounds__(256) void mfma_gemm_in_k(
    const float* __restrict__ A, const unsigned short* __restrict__ Wt,
    const float* __restrict__ bias, unsigned short* __restrict__ C, int M) {
  constexpr int K = F_IN, BK = 64;
  __shared__ __align__(16) unsigned short As[64][BK];
  __shared__ __align__(16) unsigned short Bs[128][BK];
  const int t = threadIdx.x;
  const int lane = t & 63;
  const int q = lane >> 4;
  const int l15 = lane & 15;
  const int w = t >> 6;
  const int wm = w >> 1, wn = w & 1;
  const int m0 = blockIdx.x * 64;

  f32x4 acc[2][4];
#pragma unroll
  for (int i = 0; i < 2; ++i)
#pragma unroll
    for (int j = 0; j < 4; ++j) acc[i][j] = (f32x4){0.f, 0.f, 0.f, 0.f};

  for (int k0 = 0; k0 < K; k0 += BK) {
    // A: 64 rows x 64 k, fp32->bf16 (1024 float4 chunks)
#pragma unroll
    for (int it = 0; it < 4; ++it) {
      int id = t + it * 256;
      int r = id >> 4, f4 = id & 15;
      int gm = m0 + r; if (gm >= M) gm = M - 1;
      float4 a = *(const float4*)&A[(size_t)gm * K + k0 + (f4 << 2)];
      unsigned int u0 = (unsigned int)bf16_rne(a.x) | ((unsigned int)bf16_rne(a.y) << 16);
      unsigned int u1 = (unsigned int)bf16_rne(a.z) | ((unsigned int)bf16_rne(a.w) << 16);
      int kc = f4 >> 1, half = f4 & 1;
      *(uint2*)&As[r][((kc ^ (r & 7)) << 3) + (half << 2)] = make_uint2(u0, u1);
    }
    // B: 128 n-rows x 8 chunks
#pragma unroll
    for (int it = 0; it < 4; ++it) {
      int id = t + it * 256;
      int nn = id >> 3, kc = id & 7;
      uint4 v = *(const uint4*)&Wt[(size_t)nn * K + k0 + (kc << 3)];
      *(uint4*)&Bs[nn][(kc ^ (nn & 7)) << 3] = v;
    }
    __syncthreads();
#pragma unroll
    for (int kk = 0; kk < 2; ++kk) {
      bf16x8 af[2], bfr[4];
      int kc = (kk << 2) + q;
#pragma unroll
      for (int i = 0; i < 2; ++i) {
        int m = (wm << 5) + (i << 4) + l15;
        af[i] = *(const bf16x8*)&As[m][(kc ^ (m & 7)) << 3];
      }
#pragma unroll
      for (int j = 0; j < 4; ++j) {
        int nn = (wn << 6) + (j << 4) + l15;
        bfr[j] = *(const bf16x8*)&Bs[nn][(kc ^ (nn & 7)) << 3];
      }
#pragma unroll
      for (int i = 0; i < 2; ++i)
#pragma unroll
        for (int j = 0; j < 4; ++j)
          acc[i][j] = __builtin_amdgcn_mfma_f32_16x16x32_bf16(af[i], bfr[j], acc[i][j], 0, 0, 0);
    }
    __syncthreads();
  }
#pragma unroll
  for (int j = 0; j < 4; ++j) {
    int col = (wn << 6) + (j << 4) + l15;
    float bv = bias[col];
#pragma unroll
    for (int i = 0; i < 2; ++i) {
      int rb = m0 + (wm << 5) + (i << 4) + (q << 2);
#pragma unroll
      for (int r = 0; r < 4; ++r) {
        int row = rb + r;
        if (row < M) C[(size_t)row * KTOT + col] = bf16_rne(acc[i][j][r] + bv);
      }
    }
  }
}

// ------------- aggregation: U[:,out] = A * U[:,in]; scalar chain -----------
// SMODE 0: none; 1: sout = sum w (d = A*1); 2: sout = sum w*sprev[src]
template <int SMODE>
__global__ __launch_bounds__(256) void agg_k(
    const int* __restrict__ rowp, const int2* __restrict__ csr,
    unsigned int* __restrict__ U32, int co_in, int co_out,
    const float* __restrict__ sprev, float* __restrict__ sout, int n) {
  const int lane = threadIdx.x & 63;
  const int node = (blockIdx.x << 2) + (threadIdx.x >> 6);
  if (node >= n) return;
  const int RS = KTOT / 2;   // 320 uints per row
  int beg = rowp[node], end = rowp[node + 1];
  float ax = 0.f, ay = 0.f, sacc = 0.f;
  const unsigned int* in = U32 + co_in + lane;
  int j = beg;
  for (; j + 1 < end; j += 2) {
    int2 e0 = csr[j], e1 = csr[j + 1];
    float w0 = __int_as_float(e0.y), w1 = __int_as_float(e1.y);
    unsigned int v0 = in[(size_t)e0.x * RS];
    unsigned int v1 = in[(size_t)e1.x * RS];
    ax += w0 * bf16_lo_f(v0) + w1 * bf16_lo_f(v1);
    ay += w0 * bf16_hi_f(v0) + w1 * bf16_hi_f(v1);
    if (SMODE == 1) sacc += w0 + w1;
    if (SMODE == 2) sacc += w0 * sprev[e0.x] + w1 * sprev[e1.x];
  }
  if (j < end) {
    int2 e0 = csr[j];
    float w0 = __int_as_float(e0.y);
    unsigned int v0 = in[(size_t)e0.x * RS];
    ax += w0 * bf16_lo_f(v0);
    ay += w0 * bf16_hi_f(v0);
    if (SMODE == 1) sacc += w0;
    if (SMODE == 2) sacc += w0 * sprev[e0.x];
  }
  U32[(size_t)node * RS + co_out + lane] =
      (unsigned int)bf16_rne(ax) | ((unsigned int)bf16_rne(ay) << 16);
  if (SMODE != 0 && lane == 0) sout[node] = sacc;
}

// ------ final fused GEMM: out = U[M,640] @ P[640,40] + rank-1 terms --------
__global__ __launch_bounds__(256) void final_gemm_k(
    const unsigned short* __restrict__ U, const unsigned short* __restrict__ Pbf,
    const float* __restrict__ dvec, const float* __restrict__ evec,
    const float* __restrict__ fvec, const float* __restrict__ rv,
    float* __restrict__ out, int M) {
  constexpr int K = KTOT, BK = 64;
  __shared__ __align__(16) unsigned short As[128][BK];
  __shared__ __align__(16) unsigned short Bs[NPAD][BK];
  const int t = threadIdx.x;
  const int lane = t & 63;
  const int q = lane >> 4;
  const int l15 = lane & 15;
  const int w = t >> 6;
  const int m0 = blockIdx.x * 128;

  f32x4 acc[2][3];
#pragma unroll
  for (int i = 0; i < 2; ++i)
#pragma unroll
    for (int j = 0; j < 3; ++j) acc[i][j] = (f32x4){0.f, 0.f, 0.f, 0.f};

  for (int k0 = 0; k0 < K; k0 += BK) {
#pragma unroll
    for (int it = 0; it < 4; ++it) {
      int id = t + it * 256;
      int r = id >> 3, kc = id & 7;
      int gm = m0 + r; if (gm >= M) gm = M - 1;
      uint4 v = *(const uint4*)&U[(size_t)gm * K + k0 + (kc << 3)];
      *(uint4*)&As[r][(kc ^ (r & 7)) << 3] = v;
    }
    for (int id = t; id < NPAD * 8; id += 256) {
      int nn = id >> 3, kc = id & 7;
      uint4 v = *(const uint4*)&Pbf[(size_t)nn * K + k0 + (kc << 3)];
      *(uint4*)&Bs[nn][(kc ^ (nn & 7)) << 3] = v;
    }
    __syncthreads();
#pragma unroll
    for (int kk = 0; kk < 2; ++kk) {
      bf16x8 af[2], bfr[3];
      int kc = (kk << 2) + q;
#pragma unroll
      for (int i = 0; i < 2; ++i) {
        int m = (w << 5) + (i << 4) + l15;
        af[i] = *(const bf16x8*)&As[m][(kc ^ (m & 7)) << 3];
      }
#pragma unroll
      for (int j = 0; j < 3; ++j) {
        int nn = (j << 4) + l15;
        bfr[j] = *(const bf16x8*)&Bs[nn][(kc ^ (nn & 7)) << 3];
      }
#pragma unroll
      for (int i = 0; i < 2; ++i)
#pragma unroll
        for (int j = 0; j < 3; ++j)
          acc[i][j] = __builtin_amdgcn_mfma_f32_16x16x32_bf16(af[i], bfr[j], acc[i][j], 0, 0, 0);
    }
    __syncthreads();
  }
#pragma unroll
  for (int j = 0; j < 3; ++j) {
    int col = (j << 4) + l15;
    if (col >= C_OUT) continue;
    float r1 = rv[0 * 40 + col], rd = rv[1 * 40 + col];
    float re = rv[2 * 40 + col], rf = rv[3 * 40 + col];
#pragma unroll
    for (int i = 0; i < 2; ++i) {
      int rb = m0 + (w << 5) + (i << 4) + (q << 2);
#pragma unroll
      for (int r = 0; r < 4; ++r) {
        int row = rb + r;
        if (row < M) {
          float v = acc[i][j][r] + r1 +
                    dvec[row] * rd + evec[row] * re + fvec[row] * rf;
          out[(size_t)row * C_OUT + col] = v;
        }
      }
    }
  }
}

// ------------------------------- launcher ----------------------------------

extern "C" void kernel_launch(void* const* d_in, const int* in_sizes, int n_in,
                              void* d_out, int out_size, void* d_ws, size_t ws_size,
                              hipStream_t stream) {
  const float* x     = (const float*)d_in[0];
  const int*   eidx  = (const int*)  d_in[1];
  const float* ew    = (const float*)d_in[2];
  const float* W_in  = (const float*)d_in[3];
  const float* b_in  = (const float*)d_in[4];
  const float* W_gcn = (const float*)d_in[5];
  const float* b_gcn = (const float*)d_in[6];
  const float* W_out = (const float*)d_in[7];
  const float* b_out = (const float*)d_in[8];
  float* out = (float*)d_out;

  const int* src = eidx;
  const int* dst = eidx + N_EDGES;

  char* ws = (char*)d_ws;
  size_t off = 0;
  auto alloc = [&](size_t bytes) -> void* {
    void* p = ws + off;
    off += (bytes + 255) & ~(size_t)255;
    return p;
  };
  unsigned long long* acc = (unsigned long long*)alloc((size_t)N_NODES * 8);
  int*   pos    = (int*)  alloc((size_t)N_EDGES * 4);
  int*   cnt    = (int*)  alloc((size_t)N_NODES * 4);
  int*   rowp   = (int*)  alloc((size_t)(N_NODES + 1) * 4);
  float* dinv   = (float*)alloc((size_t)N_NODES * 4);
  int*   bsum   = (int*)  alloc((size_t)256 * 4);
  int2*  csr    = (int2*) alloc((size_t)TOT_E * 8);
  unsigned short* Wt_in = (unsigned short*)alloc((size_t)F_IN * H_DIM * 2);
  unsigned short* Pbf   = (unsigned short*)alloc((size_t)NPAD * KTOT * 2);
  unsigned short* U     = (unsigned short*)alloc((size_t)N_NODES * KTOT * 2);
  float* dvec   = (float*)alloc((size_t)N_NODES * 4);
  float* evec   = (float*)alloc((size_t)N_NODES * 4);
  float* fvec   = (float*)alloc((size_t)N_NODES * 4);
  float* rv     = (float*)alloc((size_t)4 * 40 * 4);
  (void)ws_size; (void)in_sizes; (void)n_in; (void)out_size;

  dim3 b256(256);
  const int NB = (N_NODES + 255) / 256;
  const int GB64 = (N_NODES + 63) / 64;     // 782 blocks for input GEMM
  const int GB = (N_NODES + 127) / 128;     // 391 blocks for final GEMM
  const int AB = (N_NODES + 3) / 4;
  unsigned int* U32 = (unsigned int*)U;

  hipMemsetAsync(acc, 0, (size_t)N_NODES * 8, stream);
  hipMemsetAsync(rv, 0, (size_t)4 * 40 * 4, stream);
  hipMemsetAsync(Pbf, 0, (size_t)NPAD * KTOT * 2, stream);  // pad cols 40..47 = 0

  edge_pass1_k<<<(N_EDGES + 255) / 256, b256, 0, stream>>>(dst, ew, acc, pos, N_EDGES);
  node_pass_k<<<NB, b256, 0, stream>>>(acc, dinv, cnt, N_NODES);
  block_reduce_k<<<NB, b256, 0, stream>>>(cnt, bsum, N_NODES);
  scan_bsums_k<<<1, b256, 0, stream>>>(bsum, NB);
  scan_write_k<<<NB, b256, 0, stream>>>(cnt, bsum, rowp, N_NODES);
  scatter2_k<<<(TOT_E + 255) / 256, b256, 0, stream>>>(src, dst, ew, pos, dinv, rowp,
                                                       csr, N_EDGES, N_NODES);

  wcast_k<<<(F_IN * H_DIM + 255) / 256, b256, 0, stream>>>(W_in, Wt_in, F_IN, F_IN * H_DIM);
  chains_k<<<dim3(10, 4), b256, 0, stream>>>(W_gcn, b_gcn, W_out, b_out, Pbf, rv);

  // U[:,0:128] = bf16(x @ W_in + b_in)
  mfma_gemm_in_k<<<GB64, b256, 0, stream>>>(x, Wt_in, b_in, U, N_NODES);

  // u-chain: u_{p} = A * u_{p-1}; scalar chain d = A*1, e = A*d, f = A*e
  agg_k<1><<<AB, b256, 0, stream>>>(rowp, csr, U32, 0,   64,  nullptr, dvec, N_NODES);
  agg_k<2><<<AB, b256, 0, stream>>>(rowp, csr, U32, 64,  128, dvec,    evec, N_NODES);
  agg_k<2><<<AB, b256, 0, stream>>>(rowp, csr, U32, 128, 192, evec,    fvec, N_NODES);
  agg_k<0><<<AB, b256, 0, stream>>>(rowp, csr, U32, 192, 256, nullptr, nullptr, N_NODES);

  final_gemm_k<<<GB, b256, 0, stream>>>(U, Pbf, dvec, evec, fvec, rv, out, N_NODES);
}

// Round 7
// 494.540 us; speedup vs baseline: 3.1302x; 1.0610x over previous
//
#include <hip/hip_runtime.h>
#include <cstdint>
#include <cstddef>

#define N_NODES 50000
#define N_EDGES 800000
#define F_IN    512
#define H_DIM   128
#define C_OUT   40
#define TOT_E   (N_EDGES + N_NODES)
#define KTOT    640             // h | u1 | u2 | u3 | u4
#define NPAD    48              // 40 cols padded to 3 MFMA tiles

typedef __attribute__((ext_vector_type(8))) __bf16 bf16x8;
typedef __attribute__((ext_vector_type(4))) float f32x4;

__device__ __forceinline__ unsigned short bf16_rne(float f) {
  unsigned int u = __float_as_uint(f);
  u += 0x7fffu + ((u >> 16) & 1u);
  return (unsigned short)(u >> 16);
}
__device__ __forceinline__ float bf16_lo_f(unsigned int u) { return __uint_as_float(u << 16); }
__device__ __forceinline__ float bf16_hi_f(unsigned int u) { return __uint_as_float(u & 0xffff0000u); }

// ----------------------------- setup kernels -------------------------------
// Single u64 atomic per edge: bits [40..63] = count, [0..39] = 2^-24 fixed-pt
// weighted degree. Returned old count = slot of edge in its dst bucket.

__global__ void edge_pass1_k(const int* __restrict__ dst, const float* __restrict__ ew,
                             unsigned long long* __restrict__ acc,
                             int* __restrict__ pos, int e) {
  int i = blockIdx.x * blockDim.x + threadIdx.x;
  if (i < e) {
    int d = dst[i];
    unsigned long long v = (1ull << 40) |
        (unsigned long long)(ew[i] * 16777216.0f + 0.5f);
    unsigned long long old = atomicAdd(&acc[d], v);
    pos[i] = (int)(old >> 40);
  }
}

__global__ void node_pass_k(const unsigned long long* __restrict__ acc,
                            float* __restrict__ dinv, int* __restrict__ cnt, int n) {
  int i = blockIdx.x * blockDim.x + threadIdx.x;
  if (i < n) {
    unsigned long long a = acc[i];
    double dfix = (double)(a & 0xFFFFFFFFFFull);
    float deg = (float)(dfix * (1.0 / 16777216.0) + 1.0);   // +1 self-loop
    dinv[i] = rsqrtf(deg);
    cnt[i] = (int)(a >> 40) + 1;                            // +1 self-loop
  }
}

__global__ __launch_bounds__(256) void block_reduce_k(const int* __restrict__ cnt,
                                                      int* bsum, int n) {
  __shared__ int s[256];
  int t = threadIdx.x;
  int i = blockIdx.x * 256 + t;
  s[t] = (i < n) ? cnt[i] : 0;
  __syncthreads();
  for (int off = 128; off; off >>= 1) {
    if (t < off) s[t] += s[t + off];
    __syncthreads();
  }
  if (t == 0) bsum[blockIdx.x] = s[0];
}

__global__ __launch_bounds__(256) void scan_bsums_k(int* bsum, int nb) {
  __shared__ int s[256];
  int t = threadIdx.x;
  s[t] = (t < nb) ? bsum[t] : 0;
  __syncthreads();
  for (int off = 1; off < 256; off <<= 1) {
    int v = (t >= off) ? s[t - off] : 0;
    __syncthreads();
    s[t] += v;
    __syncthreads();
  }
  if (t < nb) bsum[t] = (t == 0) ? 0 : s[t - 1];
}

__global__ __launch_bounds__(256) void scan_write_k(const int* __restrict__ cnt,
                                                    const int* __restrict__ bsum,
                                                    int* row_ptr, int n) {
  __shared__ int s[256];
  int t = threadIdx.x;
  int i = blockIdx.x * 256 + t;
  int c = (i < n) ? cnt[i] : 0;
  s[t] = c;
  __syncthreads();
  for (int off = 1; off < 256; off <<= 1) {
    int v = (t >= off) ? s[t - off] : 0;
    __syncthreads();
    s[t] += v;
    __syncthreads();
  }
  int ex = bsum[blockIdx.x] + ((t == 0) ? 0 : s[t - 1]);
  if (i < n) row_ptr[i] = ex;
  if (i == n - 1) row_ptr[n] = ex + c;
}

__global__ void scatter2_k(const int* __restrict__ src, const int* __restrict__ dst,
                           const float* __restrict__ ew, const int* __restrict__ pos,
                           const float* __restrict__ dinv, const int* __restrict__ rowp,
                           int2* __restrict__ csr, int e, int n) {
  int i = blockIdx.x * blockDim.x + threadIdx.x;
  if (i < e) {
    int s = src[i], d = dst[i];
    float w = dinv[s] * ew[i] * dinv[d];
    csr[rowp[d] + pos[i]] = make_int2(s, __float_as_int(w));
  } else if (i < e + n) {
    int v = i - e;
    float di = dinv[v];
    csr[rowp[v + 1] - 1] = make_int2(v, __float_as_int(di * di));  // self-loop last
  }
}

// ------------------- weight transpose+cast: Wt[n][k] = bf16(W[k][n]) -------
__global__ void wcast_k(const float* __restrict__ W, unsigned short* __restrict__ Wt,
                        int K, int total) {
  int i = blockIdx.x * 256 + threadIdx.x;
  if (i >= total) return;
  int per = K * 128;
  int b = i / per;
  int rem = i - b * per;
  int k = rem >> 7, nn = rem & 127;
  Wt[(size_t)b * per + (size_t)nn * K + k] = bf16_rne(W[i]);
}

// ---- weight-chain precompute: P slices [KTOT x 48] bf16 + rank-1 rows -----
// Column-parallel: grid (10, 4). blockIdx.y = branch b (j=b+1), blockIdx.x =
// column group (4 of 40 cols). Each block evolves a 128x4 slice S <- W_k * S.
__global__ __launch_bounds__(256) void chains_k(
    const float* __restrict__ W_gcn, const float* __restrict__ b_gcn,
    const float* __restrict__ W_out, const float* __restrict__ b_out,
    unsigned short* __restrict__ Pbf, float* __restrict__ rv) {
  __shared__ float T0[128 * 4];
  __shared__ float T1[128 * 4];
  const int b = blockIdx.y;          // 0..3
  const int j = b + 1;
  const int c0 = blockIdx.x * 4;     // col group base
  const int ks_all[4][4] = {{0, -1, -1, -1}, {1, 2, -1, -1}, {3, 4, 5, -1}, {6, 7, 8, 9}};
  const int t = threadIdx.x;
  const int lane = t & 63;
  const int wv = t >> 6;             // wave 0..3

  for (int idx = t; idx < 512; idx += 256) {
    int r = idx >> 2, c = idx & 3;
    T0[idx] = W_out[(size_t)(j * 128 + r) * 40 + c0 + c];
  }
  __syncthreads();
  float* Tc = T0;
  float* Tn = T1;
  for (int step = 0; step < j; ++step) {
    int kw = ks_all[b][j - 1 - step];
    {
      float s = b_gcn[kw * 128 + lane] * Tc[lane * 4 + wv] +
                b_gcn[kw * 128 + 64 + lane] * Tc[(64 + lane) * 4 + wv];
      for (int o = 32; o; o >>= 1) s += __shfl_down(s, o);
      if (lane == 0) atomicAdd(&rv[step * 40 + c0 + wv], s);
    }
    const float* W = W_gcn + (size_t)kw * 128 * 128;
    int r = t & 127;
    int ch = (t >> 7) << 1;          // 0 or 2
    float a0 = 0.f, a1 = 0.f;
    for (int k = 0; k < 128; k += 4) {
      float4 w4 = *(const float4*)&W[(size_t)r * 128 + k];
      a0 += w4.x * Tc[(k + 0) * 4 + ch] + w4.y * Tc[(k + 1) * 4 + ch] +
            w4.z * Tc[(k + 2) * 4 + ch] + w4.w * Tc[(k + 3) * 4 + ch];
      a1 += w4.x * Tc[(k + 0) * 4 + ch + 1] + w4.y * Tc[(k + 1) * 4 + ch + 1] +
            w4.z * Tc[(k + 2) * 4 + ch + 1] + w4.w * Tc[(k + 3) * 4 + ch + 1];
    }
    Tn[r * 4 + ch] = a0;
    Tn[r * 4 + ch + 1] = a1;
    __syncthreads();
    float* tmp = Tc; Tc = Tn; Tn = tmp;
  }
  for (int idx = t; idx < 512; idx += 256) {
    int r = idx >> 2, c = idx & 3;
    Pbf[(size_t)(c0 + c) * KTOT + j * 128 + r] = bf16_rne(Tc[idx]);
  }
  if (b == 0) {
    for (int idx = t; idx < 512; idx += 256) {
      int r = idx >> 2, c = idx & 3;
      Pbf[(size_t)(c0 + c) * KTOT + r] = bf16_rne(W_out[(size_t)r * 40 + c0 + c]);
    }
    if (blockIdx.x == 0 && t < 40) atomicAdd(&rv[t], b_out[t]);   // row_1 += b_out
  }
}

// ------------- input MFMA GEMM: U[:,0:128] = bf16(x @ W_in + b_in) ---------
// 64x128 tile, BK=64. Software-pipelined: global loads for tile k+1 issue
// right after the staging barrier, overlapping the MFMA phase (round-6 showed
// the serial load->cast->LDS->MFMA chain exposed full load latency per iter:
// MfmaUtil 3.9%, VALUBusy 10%, HBM 14% -- all idle).
__global__ __launch_bounds__(256) void mfma_gemm_in_k(
    const float* __restrict__ A, const unsigned short* __restrict__ Wt,
    const float* __restrict__ bias, unsigned short* __restrict__ C, int M) {
  constexpr int K = F_IN, BK = 64;
  __shared__ __align__(16) unsigned short As[64][BK];
  __shared__ __align__(16) unsigned short Bs[128][BK];
  const int t = threadIdx.x;
  const int lane = t & 63;
  const int q = lane >> 4;
  const int l15 = lane & 15;
  const int w = t >> 6;
  const int wm = w >> 1, wn = w & 1;
  const int m0 = blockIdx.x * 64;

  int agm[4];
#pragma unroll
  for (int it = 0; it < 4; ++it) {
    int id = t + it * 256;
    int gm = m0 + (id >> 4); if (gm >= M) gm = M - 1;
    agm[it] = gm;
  }

  float4 a_reg[4];
  uint4  b_reg[4];
  // prologue: prefetch tile 0
#pragma unroll
  for (int it = 0; it < 4; ++it) {
    int f4 = (t + it * 256) & 15;
    a_reg[it] = *(const float4*)&A[(size_t)agm[it] * K + (f4 << 2)];
  }
#pragma unroll
  for (int it = 0; it < 4; ++it) {
    int id = t + it * 256;
    int nn = id >> 3, kc = id & 7;
    b_reg[it] = *(const uint4*)&Wt[(size_t)nn * K + (kc << 3)];
  }

  f32x4 acc[2][4];
#pragma unroll
  for (int i = 0; i < 2; ++i)
#pragma unroll
    for (int j = 0; j < 4; ++j) acc[i][j] = (f32x4){0.f, 0.f, 0.f, 0.f};

  for (int k0 = 0; k0 < K; k0 += BK) {
    // ---- commit prefetched regs to LDS (cast A fp32->bf16) ----
#pragma unroll
    for (int it = 0; it < 4; ++it) {
      int id = t + it * 256;
      int r = id >> 4, f4 = id & 15;
      float4 a = a_reg[it];
      unsigned int u0 = (unsigned int)bf16_rne(a.x) | ((unsigned int)bf16_rne(a.y) << 16);
      unsigned int u1 = (unsigned int)bf16_rne(a.z) | ((unsigned int)bf16_rne(a.w) << 16);
      int kc = f4 >> 1, half = f4 & 1;
      *(uint2*)&As[r][((kc ^ (r & 7)) << 3) + (half << 2)] = make_uint2(u0, u1);
    }
#pragma unroll
    for (int it = 0; it < 4; ++it) {
      int id = t + it * 256;
      int nn = id >> 3, kc = id & 7;
      *(uint4*)&Bs[nn][(kc ^ (nn & 7)) << 3] = b_reg[it];
    }
    __syncthreads();
    // ---- issue next tile's loads; waitcnt lands before next LDS store ----
    if (k0 + BK < K) {
      int kn = k0 + BK;
#pragma unroll
      for (int it = 0; it < 4; ++it) {
        int f4 = (t + it * 256) & 15;
        a_reg[it] = *(const float4*)&A[(size_t)agm[it] * K + kn + (f4 << 2)];
      }
#pragma unroll
      for (int it = 0; it < 4; ++it) {
        int id = t + it * 256;
        int nn = id >> 3, kc = id & 7;
        b_reg[it] = *(const uint4*)&Wt[(size_t)nn * K + kn + (kc << 3)];
      }
    }
    // ---- compute from LDS (overlaps the loads above) ----
#pragma unroll
    for (int kk = 0; kk < 2; ++kk) {
      bf16x8 af[2], bfr[4];
      int kc = (kk << 2) + q;
#pragma unroll
      for (int i = 0; i < 2; ++i) {
        int m = (wm << 5) + (i << 4) + l15;
        af[i] = *(const bf16x8*)&As[m][(kc ^ (m & 7)) << 3];
      }
#pragma unroll
      for (int j = 0; j < 4; ++j) {
        int nn = (wn << 6) + (j << 4) + l15;
        bfr[j] = *(const bf16x8*)&Bs[nn][(kc ^ (nn & 7)) << 3];
      }
#pragma unroll
      for (int i = 0; i < 2; ++i)
#pragma unroll
        for (int j = 0; j < 4; ++j)
          acc[i][j] = __builtin_amdgcn_mfma_f32_16x16x32_bf16(af[i], bfr[j], acc[i][j], 0, 0, 0);
    }
    __syncthreads();
  }
#pragma unroll
  for (int j = 0; j < 4; ++j) {
    int col = (wn << 6) + (j << 4) + l15;
    float bv = bias[col];
#pragma unroll
    for (int i = 0; i < 2; ++i) {
      int rb = m0 + (wm << 5) + (i << 4) + (q << 2);
#pragma unroll
      for (int r = 0; r < 4; ++r) {
        int row = rb + r;
        if (row < M) C[(size_t)row * KTOT + col] = bf16_rne(acc[i][j][r] + bv);
      }
    }
  }
}

// ------------- aggregation: U[:,out] = A * U[:,in]; scalar chain -----------
// SMODE 0: none; 1: sout = sum w (d = A*1); 2: sout = sum w*sprev[src]
// 4-edge unroll: 4 outstanding 256B row-gathers per wave (round-6 had 2 ->
// ~8 serial L3 round-trips per node at avg degree 17).
template <int SMODE>
__global__ __launch_bounds__(256) void agg_k(
    const int* __restrict__ rowp, const int2* __restrict__ csr,
    unsigned int* __restrict__ U32, int co_in, int co_out,
    const float* __restrict__ sprev, float* __restrict__ sout, int n) {
  const int lane = threadIdx.x & 63;
  const int node = (blockIdx.x << 2) + (threadIdx.x >> 6);
  if (node >= n) return;
  const int RS = KTOT / 2;   // 320 uints per row
  int beg = rowp[node], end = rowp[node + 1];
  float ax = 0.f, ay = 0.f, sacc = 0.f;
  const unsigned int* in = U32 + co_in + lane;
  int j = beg;
  for (; j + 3 < end; j += 4) {
    int2 e0 = csr[j], e1 = csr[j + 1], e2 = csr[j + 2], e3 = csr[j + 3];
    unsigned int v0 = in[(size_t)e0.x * RS];
    unsigned int v1 = in[(size_t)e1.x * RS];
    unsigned int v2 = in[(size_t)e2.x * RS];
    unsigned int v3 = in[(size_t)e3.x * RS];
    float w0 = __int_as_float(e0.y), w1 = __int_as_float(e1.y);
    float w2 = __int_as_float(e2.y), w3 = __int_as_float(e3.y);
    ax += w0 * bf16_lo_f(v0) + w1 * bf16_lo_f(v1) +
          w2 * bf16_lo_f(v2) + w3 * bf16_lo_f(v3);
    ay += w0 * bf16_hi_f(v0) + w1 * bf16_hi_f(v1) +
          w2 * bf16_hi_f(v2) + w3 * bf16_hi_f(v3);
    if (SMODE == 1) sacc += (w0 + w1) + (w2 + w3);
    if (SMODE == 2) sacc += w0 * sprev[e0.x] + w1 * sprev[e1.x] +
                            w2 * sprev[e2.x] + w3 * sprev[e3.x];
  }
  for (; j < end; ++j) {
    int2 e0 = csr[j];
    float w0 = __int_as_float(e0.y);
    unsigned int v0 = in[(size_t)e0.x * RS];
    ax += w0 * bf16_lo_f(v0);
    ay += w0 * bf16_hi_f(v0);
    if (SMODE == 1) sacc += w0;
    if (SMODE == 2) sacc += w0 * sprev[e0.x];
  }
  U32[(size_t)node * RS + co_out + lane] =
      (unsigned int)bf16_rne(ax) | ((unsigned int)bf16_rne(ay) << 16);
  if (SMODE != 0 && lane == 0) sout[node] = sacc;
}

// ------ final fused GEMM: out = U[M,640] @ P[640,40] + rank-1 terms --------
__global__ __launch_bounds__(256) void final_gemm_k(
    const unsigned short* __restrict__ U, const unsigned short* __restrict__ Pbf,
    const float* __restrict__ dvec, const float* __restrict__ evec,
    const float* __restrict__ fvec, const float* __restrict__ rv,
    float* __restrict__ out, int M) {
  constexpr int K = KTOT, BK = 64;
  __shared__ __align__(16) unsigned short As[128][BK];
  __shared__ __align__(16) unsigned short Bs[NPAD][BK];
  const int t = threadIdx.x;
  const int lane = t & 63;
  const int q = lane >> 4;
  const int l15 = lane & 15;
  const int w = t >> 6;
  const int m0 = blockIdx.x * 128;

  f32x4 acc[2][3];
#pragma unroll
  for (int i = 0; i < 2; ++i)
#pragma unroll
    for (int j = 0; j < 3; ++j) acc[i][j] = (f32x4){0.f, 0.f, 0.f, 0.f};

  for (int k0 = 0; k0 < K; k0 += BK) {
#pragma unroll
    for (int it = 0; it < 4; ++it) {
      int id = t + it * 256;
      int r = id >> 3, kc = id & 7;
      int gm = m0 + r; if (gm >= M) gm = M - 1;
      uint4 v = *(const uint4*)&U[(size_t)gm * K + k0 + (kc << 3)];
      *(uint4*)&As[r][(kc ^ (r & 7)) << 3] = v;
    }
    for (int id = t; id < NPAD * 8; id += 256) {
      int nn = id >> 3, kc = id & 7;
      uint4 v = *(const uint4*)&Pbf[(size_t)nn * K + k0 + (kc << 3)];
      *(uint4*)&Bs[nn][(kc ^ (nn & 7)) << 3] = v;
    }
    __syncthreads();
#pragma unroll
    for (int kk = 0; kk < 2; ++kk) {
      bf16x8 af[2], bfr[3];
      int kc = (kk << 2) + q;
#pragma unroll
      for (int i = 0; i < 2; ++i) {
        int m = (w << 5) + (i << 4) + l15;
        af[i] = *(const bf16x8*)&As[m][(kc ^ (m & 7)) << 3];
      }
#pragma unroll
      for (int j = 0; j < 3; ++j) {
        int nn = (j << 4) + l15;
        bfr[j] = *(const bf16x8*)&Bs[nn][(kc ^ (nn & 7)) << 3];
      }
#pragma unroll
      for (int i = 0; i < 2; ++i)
#pragma unroll
        for (int j = 0; j < 3; ++j)
          acc[i][j] = __builtin_amdgcn_mfma_f32_16x16x32_bf16(af[i], bfr[j], acc[i][j], 0, 0, 0);
    }
    __syncthreads();
  }
#pragma unroll
  for (int j = 0; j < 3; ++j) {
    int col = (j << 4) + l15;
    if (col >= C_OUT) continue;
    float r1 = rv[0 * 40 + col], rd = rv[1 * 40 + col];
    float re = rv[2 * 40 + col], rf = rv[3 * 40 + col];
#pragma unroll
    for (int i = 0; i < 2; ++i) {
      int rb = m0 + (w << 5) + (i << 4) + (q << 2);
#pragma unroll
      for (int r = 0; r < 4; ++r) {
        int row = rb + r;
        if (row < M) {
          float v = acc[i][j][r] + r1 +
                    dvec[row] * rd + evec[row] * re + fvec[row] * rf;
          out[(size_t)row * C_OUT + col] = v;
        }
      }
    }
  }
}

// ------------------------------- launcher ----------------------------------

extern "C" void kernel_launch(void* const* d_in, const int* in_sizes, int n_in,
                              void* d_out, int out_size, void* d_ws, size_t ws_size,
                              hipStream_t stream) {
  const float* x     = (const float*)d_in[0];
  const int*   eidx  = (const int*)  d_in[1];
  const float* ew    = (const float*)d_in[2];
  const float* W_in  = (const float*)d_in[3];
  const float* b_in  = (const float*)d_in[4];
  const float* W_gcn = (const float*)d_in[5];
  const float* b_gcn = (const float*)d_in[6];
  const float* W_out = (const float*)d_in[7];
  const float* b_out = (const float*)d_in[8];
  float* out = (float*)d_out;

  const int* src = eidx;
  const int* dst = eidx + N_EDGES;

  char* ws = (char*)d_ws;
  size_t off = 0;
  auto alloc = [&](size_t bytes) -> void* {
    void* p = ws + off;
    off += (bytes + 255) & ~(size_t)255;
    return p;
  };
  unsigned long long* acc = (unsigned long long*)alloc((size_t)N_NODES * 8);
  int*   pos    = (int*)  alloc((size_t)N_EDGES * 4);
  int*   cnt    = (int*)  alloc((size_t)N_NODES * 4);
  int*   rowp   = (int*)  alloc((size_t)(N_NODES + 1) * 4);
  float* dinv   = (float*)alloc((size_t)N_NODES * 4);
  int*   bsum   = (int*)  alloc((size_t)256 * 4);
  int2*  csr    = (int2*) alloc((size_t)TOT_E * 8);
  unsigned short* Wt_in = (unsigned short*)alloc((size_t)F_IN * H_DIM * 2);
  unsigned short* Pbf   = (unsigned short*)alloc((size_t)NPAD * KTOT * 2);
  unsigned short* U     = (unsigned short*)alloc((size_t)N_NODES * KTOT * 2);
  float* dvec   = (float*)alloc((size_t)N_NODES * 4);
  float* evec   = (float*)alloc((size_t)N_NODES * 4);
  float* fvec   = (float*)alloc((size_t)N_NODES * 4);
  float* rv     = (float*)alloc((size_t)4 * 40 * 4);
  (void)ws_size; (void)in_sizes; (void)n_in; (void)out_size;

  dim3 b256(256);
  const int NB = (N_NODES + 255) / 256;
  const int GB64 = (N_NODES + 63) / 64;     // 782 blocks for input GEMM
  const int GB = (N_NODES + 127) / 128;     // 391 blocks for final GEMM
  const int AB = (N_NODES + 3) / 4;
  unsigned int* U32 = (unsigned int*)U;

  hipMemsetAsync(acc, 0, (size_t)N_NODES * 8, stream);
  hipMemsetAsync(rv, 0, (size_t)4 * 40 * 4, stream);
  hipMemsetAsync(Pbf, 0, (size_t)NPAD * KTOT * 2, stream);  // pad cols 40..47 = 0

  edge_pass1_k<<<(N_EDGES + 255) / 256, b256, 0, stream>>>(dst, ew, acc, pos, N_EDGES);
  node_pass_k<<<NB, b256, 0, stream>>>(acc, dinv, cnt, N_NODES);
  block_reduce_k<<<NB, b256, 0, stream>>>(cnt, bsum, N_NODES);
  scan_bsums_k<<<1, b256, 0, stream>>>(bsum, NB);
  scan_write_k<<<NB, b256, 0, stream>>>(cnt, bsum, rowp, N_NODES);
  scatter2_k<<<(TOT_E + 255) / 256, b256, 0, stream>>>(src, dst, ew, pos, dinv, rowp,
                                                       csr, N_EDGES, N_NODES);

  wcast_k<<<(F_IN * H_DIM + 255) / 256, b256, 0, stream>>>(W_in, Wt_in, F_IN, F_IN * H_DIM);
  chains_k<<<dim3(10, 4), b256, 0, stream>>>(W_gcn, b_gcn, W_out, b_out, Pbf, rv);

  // U[:,0:128] = bf16(x @ W_in + b_in)
  mfma_gemm_in_k<<<GB64, b256, 0, stream>>>(x, Wt_in, b_in, U, N_NODES);

  // u-chain: u_{p} = A * u_{p-1}; scalar chain d = A*1, e = A*d, f = A*e
  agg_k<1><<<AB, b256, 0, stream>>>(rowp, csr, U32, 0,   64,  nullptr, dvec, N_NODES);
  agg_k<2><<<AB, b256, 0, stream>>>(rowp, csr, U32, 64,  128, dvec,    evec, N_NODES);
  agg_k<2><<<AB, b256, 0, stream>>>(rowp, csr, U32, 128, 192, evec,    fvec, N_NODES);
  agg_k<0><<<AB, b256, 0, stream>>>(rowp, csr, U32, 192, 256, nullptr, nullptr, N_NODES);

  final_gemm_k<<<GB, b256, 0, stream>>>(U, Pbf, dvec, evec, fvec, rv, out, N_NODES);
}

// Round 8
// 494.487 us; speedup vs baseline: 3.1305x; 1.0001x over previous
//
#include <hip/hip_runtime.h>
#include <cstdint>
#include <cstddef>

#define N_NODES 50000
#define N_EDGES 800000
#define F_IN    512
#define H_DIM   128
#define C_OUT   40
#define TOT_E   (N_EDGES + N_NODES)
#define KTOT    640             // h | u1 | u2 | u3 | u4
#define NPAD    48              // 40 cols padded to 3 MFMA tiles

typedef __attribute__((ext_vector_type(8))) __bf16 bf16x8;
typedef __attribute__((ext_vector_type(4))) float f32x4;

__device__ __forceinline__ unsigned short bf16_rne(float f) {
  unsigned int u = __float_as_uint(f);
  u += 0x7fffu + ((u >> 16) & 1u);
  return (unsigned short)(u >> 16);
}
__device__ __forceinline__ float bf16_lo_f(unsigned int u) { return __uint_as_float(u << 16); }
__device__ __forceinline__ float bf16_hi_f(unsigned int u) { return __uint_as_float(u & 0xffff0000u); }

// ----------------------------- setup kernels -------------------------------
// Single u64 atomic per edge: bits [40..63] = count, [0..39] = 2^-24 fixed-pt
// weighted degree. Returned old count = slot of edge in its dst bucket.

__global__ void edge_pass1_k(const int* __restrict__ dst, const float* __restrict__ ew,
                             unsigned long long* __restrict__ acc,
                             int* __restrict__ pos, int e) {
  int i = blockIdx.x * blockDim.x + threadIdx.x;
  if (i < e) {
    int d = dst[i];
    unsigned long long v = (1ull << 40) |
        (unsigned long long)(ew[i] * 16777216.0f + 0.5f);
    unsigned long long old = atomicAdd(&acc[d], v);
    pos[i] = (int)(old >> 40);
  }
}

__global__ void node_pass_k(const unsigned long long* __restrict__ acc,
                            float* __restrict__ dinv, int* __restrict__ cnt, int n) {
  int i = blockIdx.x * blockDim.x + threadIdx.x;
  if (i < n) {
    unsigned long long a = acc[i];
    double dfix = (double)(a & 0xFFFFFFFFFFull);
    float deg = (float)(dfix * (1.0 / 16777216.0) + 1.0);   // +1 self-loop
    dinv[i] = rsqrtf(deg);
    cnt[i] = (int)(a >> 40) + 1;                            // +1 self-loop
  }
}

__global__ __launch_bounds__(256) void block_reduce_k(const int* __restrict__ cnt,
                                                      int* bsum, int n) {
  __shared__ int s[256];
  int t = threadIdx.x;
  int i = blockIdx.x * 256 + t;
  s[t] = (i < n) ? cnt[i] : 0;
  __syncthreads();
  for (int off = 128; off; off >>= 1) {
    if (t < off) s[t] += s[t + off];
    __syncthreads();
  }
  if (t == 0) bsum[blockIdx.x] = s[0];
}

__global__ __launch_bounds__(256) void scan_bsums_k(int* bsum, int nb) {
  __shared__ int s[256];
  int t = threadIdx.x;
  s[t] = (t < nb) ? bsum[t] : 0;
  __syncthreads();
  for (int off = 1; off < 256; off <<= 1) {
    int v = (t >= off) ? s[t - off] : 0;
    __syncthreads();
    s[t] += v;
    __syncthreads();
  }
  if (t < nb) bsum[t] = (t == 0) ? 0 : s[t - 1];
}

__global__ __launch_bounds__(256) void scan_write_k(const int* __restrict__ cnt,
                                                    const int* __restrict__ bsum,
                                                    int* row_ptr, int n) {
  __shared__ int s[256];
  int t = threadIdx.x;
  int i = blockIdx.x * 256 + t;
  int c = (i < n) ? cnt[i] : 0;
  s[t] = c;
  __syncthreads();
  for (int off = 1; off < 256; off <<= 1) {
    int v = (t >= off) ? s[t - off] : 0;
    __syncthreads();
    s[t] += v;
    __syncthreads();
  }
  int ex = bsum[blockIdx.x] + ((t == 0) ? 0 : s[t - 1]);
  if (i < n) row_ptr[i] = ex;
  if (i == n - 1) row_ptr[n] = ex + c;
}

__global__ void scatter2_k(const int* __restrict__ src, const int* __restrict__ dst,
                           const float* __restrict__ ew, const int* __restrict__ pos,
                           const float* __restrict__ dinv, const int* __restrict__ rowp,
                           int2* __restrict__ csr, int e, int n) {
  int i = blockIdx.x * blockDim.x + threadIdx.x;
  if (i < e) {
    int s = src[i], d = dst[i];
    float w = dinv[s] * ew[i] * dinv[d];
    csr[rowp[d] + pos[i]] = make_int2(s, __float_as_int(w));
  } else if (i < e + n) {
    int v = i - e;
    float di = dinv[v];
    csr[rowp[v + 1] - 1] = make_int2(v, __float_as_int(di * di));  // self-loop last
  }
}

// ------------------- weight transpose+cast: Wt[n][k] = bf16(W[k][n]) -------
__global__ void wcast_k(const float* __restrict__ W, unsigned short* __restrict__ Wt,
                        int K, int total) {
  int i = blockIdx.x * 256 + threadIdx.x;
  if (i >= total) return;
  int per = K * 128;
  int b = i / per;
  int rem = i - b * per;
  int k = rem >> 7, nn = rem & 127;
  Wt[(size_t)b * per + (size_t)nn * K + k] = bf16_rne(W[i]);
}

// ---- weight-chain precompute: P slices [KTOT x 48] bf16 + rank-1 rows -----
// Column-parallel: grid (10, 4). blockIdx.y = branch b (j=b+1), blockIdx.x =
// column group (4 of 40 cols). Each block evolves a 128x4 slice S <- W_k * S.
__global__ __launch_bounds__(256) void chains_k(
    const float* __restrict__ W_gcn, const float* __restrict__ b_gcn,
    const float* __restrict__ W_out, const float* __restrict__ b_out,
    unsigned short* __restrict__ Pbf, float* __restrict__ rv) {
  __shared__ float T0[128 * 4];
  __shared__ float T1[128 * 4];
  const int b = blockIdx.y;          // 0..3
  const int j = b + 1;
  const int c0 = blockIdx.x * 4;     // col group base
  const int ks_all[4][4] = {{0, -1, -1, -1}, {1, 2, -1, -1}, {3, 4, 5, -1}, {6, 7, 8, 9}};
  const int t = threadIdx.x;
  const int lane = t & 63;
  const int wv = t >> 6;             // wave 0..3

  for (int idx = t; idx < 512; idx += 256) {
    int r = idx >> 2, c = idx & 3;
    T0[idx] = W_out[(size_t)(j * 128 + r) * 40 + c0 + c];
  }
  __syncthreads();
  float* Tc = T0;
  float* Tn = T1;
  for (int step = 0; step < j; ++step) {
    int kw = ks_all[b][j - 1 - step];
    {
      float s = b_gcn[kw * 128 + lane] * Tc[lane * 4 + wv] +
                b_gcn[kw * 128 + 64 + lane] * Tc[(64 + lane) * 4 + wv];
      for (int o = 32; o; o >>= 1) s += __shfl_down(s, o);
      if (lane == 0) atomicAdd(&rv[step * 40 + c0 + wv], s);
    }
    const float* W = W_gcn + (size_t)kw * 128 * 128;
    int r = t & 127;
    int ch = (t >> 7) << 1;          // 0 or 2
    float a0 = 0.f, a1 = 0.f;
    for (int k = 0; k < 128; k += 4) {
      float4 w4 = *(const float4*)&W[(size_t)r * 128 + k];
      a0 += w4.x * Tc[(k + 0) * 4 + ch] + w4.y * Tc[(k + 1) * 4 + ch] +
            w4.z * Tc[(k + 2) * 4 + ch] + w4.w * Tc[(k + 3) * 4 + ch];
      a1 += w4.x * Tc[(k + 0) * 4 + ch + 1] + w4.y * Tc[(k + 1) * 4 + ch + 1] +
            w4.z * Tc[(k + 2) * 4 + ch + 1] + w4.w * Tc[(k + 3) * 4 + ch + 1];
    }
    Tn[r * 4 + ch] = a0;
    Tn[r * 4 + ch + 1] = a1;
    __syncthreads();
    float* tmp = Tc; Tc = Tn; Tn = tmp;
  }
  for (int idx = t; idx < 512; idx += 256) {
    int r = idx >> 2, c = idx & 3;
    Pbf[(size_t)(c0 + c) * KTOT + j * 128 + r] = bf16_rne(Tc[idx]);
  }
  if (b == 0) {
    for (int idx = t; idx < 512; idx += 256) {
      int r = idx >> 2, c = idx & 3;
      Pbf[(size_t)(c0 + c) * KTOT + r] = bf16_rne(W_out[(size_t)r * 40 + c0 + c]);
    }
    if (blockIdx.x == 0 && t < 40) atomicAdd(&rv[t], b_out[t]);   // row_1 += b_out
  }
}

// ------------- input MFMA GEMM: U[:,0:128] = bf16(x @ W_in + b_in) ---------
// 64x128 tile, BK=64, register-prefetch pipeline. __launch_bounds__(256,4):
// round-7 showed the compiler capping VGPRs at 68 (7+ waves/EU target) and
// SPILLING the prefetch regs to scratch -- WRITE_SIZE 15->92 MB (+77 MB ==
// a_reg 64B x 7 iters x 200k threads), dur 62->77 us. 4 waves/EU -> 128 VGPR
// budget, no spill, pipeline actually lives in registers.
__global__ __launch_bounds__(256, 4) void mfma_gemm_in_k(
    const float* __restrict__ A, const unsigned short* __restrict__ Wt,
    const float* __restrict__ bias, unsigned short* __restrict__ C, int M) {
  constexpr int K = F_IN, BK = 64;
  __shared__ __align__(16) unsigned short As[64][BK];
  __shared__ __align__(16) unsigned short Bs[128][BK];
  const int t = threadIdx.x;
  const int lane = t & 63;
  const int q = lane >> 4;
  const int l15 = lane & 15;
  const int w = t >> 6;
  const int wm = w >> 1, wn = w & 1;
  const int m0 = blockIdx.x * 64;

  int agm[4];
#pragma unroll
  for (int it = 0; it < 4; ++it) {
    int id = t + it * 256;
    int gm = m0 + (id >> 4); if (gm >= M) gm = M - 1;
    agm[it] = gm;
  }

  float4 a_reg[4];
  uint4  b_reg[4];
  // prologue: prefetch tile 0
#pragma unroll
  for (int it = 0; it < 4; ++it) {
    int f4 = (t + it * 256) & 15;
    a_reg[it] = *(const float4*)&A[(size_t)agm[it] * K + (f4 << 2)];
  }
#pragma unroll
  for (int it = 0; it < 4; ++it) {
    int id = t + it * 256;
    int nn = id >> 3, kc = id & 7;
    b_reg[it] = *(const uint4*)&Wt[(size_t)nn * K + (kc << 3)];
  }

  f32x4 acc[2][4];
#pragma unroll
  for (int i = 0; i < 2; ++i)
#pragma unroll
    for (int j = 0; j < 4; ++j) acc[i][j] = (f32x4){0.f, 0.f, 0.f, 0.f};

  for (int k0 = 0; k0 < K; k0 += BK) {
    // ---- commit prefetched regs to LDS (cast A fp32->bf16) ----
#pragma unroll
    for (int it = 0; it < 4; ++it) {
      int id = t + it * 256;
      int r = id >> 4, f4 = id & 15;
      float4 a = a_reg[it];
      unsigned int u0 = (unsigned int)bf16_rne(a.x) | ((unsigned int)bf16_rne(a.y) << 16);
      unsigned int u1 = (unsigned int)bf16_rne(a.z) | ((unsigned int)bf16_rne(a.w) << 16);
      int kc = f4 >> 1, half = f4 & 1;
      *(uint2*)&As[r][((kc ^ (r & 7)) << 3) + (half << 2)] = make_uint2(u0, u1);
    }
#pragma unroll
    for (int it = 0; it < 4; ++it) {
      int id = t + it * 256;
      int nn = id >> 3, kc = id & 7;
      *(uint4*)&Bs[nn][(kc ^ (nn & 7)) << 3] = b_reg[it];
    }
    __syncthreads();
    // ---- issue next tile's loads; waitcnt lands before next LDS store ----
    if (k0 + BK < K) {
      int kn = k0 + BK;
#pragma unroll
      for (int it = 0; it < 4; ++it) {
        int f4 = (t + it * 256) & 15;
        a_reg[it] = *(const float4*)&A[(size_t)agm[it] * K + kn + (f4 << 2)];
      }
#pragma unroll
      for (int it = 0; it < 4; ++it) {
        int id = t + it * 256;
        int nn = id >> 3, kc = id & 7;
        b_reg[it] = *(const uint4*)&Wt[(size_t)nn * K + kn + (kc << 3)];
      }
    }
    // ---- compute from LDS (overlaps the loads above) ----
#pragma unroll
    for (int kk = 0; kk < 2; ++kk) {
      bf16x8 af[2], bfr[4];
      int kc = (kk << 2) + q;
#pragma unroll
      for (int i = 0; i < 2; ++i) {
        int m = (wm << 5) + (i << 4) + l15;
        af[i] = *(const bf16x8*)&As[m][(kc ^ (m & 7)) << 3];
      }
#pragma unroll
      for (int j = 0; j < 4; ++j) {
        int nn = (wn << 6) + (j << 4) + l15;
        bfr[j] = *(const bf16x8*)&Bs[nn][(kc ^ (nn & 7)) << 3];
      }
#pragma unroll
      for (int i = 0; i < 2; ++i)
#pragma unroll
        for (int j = 0; j < 4; ++j)
          acc[i][j] = __builtin_amdgcn_mfma_f32_16x16x32_bf16(af[i], bfr[j], acc[i][j], 0, 0, 0);
    }
    __syncthreads();
  }
#pragma unroll
  for (int j = 0; j < 4; ++j) {
    int col = (wn << 6) + (j << 4) + l15;
    float bv = bias[col];
#pragma unroll
    for (int i = 0; i < 2; ++i) {
      int rb = m0 + (wm << 5) + (i << 4) + (q << 2);
#pragma unroll
      for (int r = 0; r < 4; ++r) {
        int row = rb + r;
        if (row < M) C[(size_t)row * KTOT + col] = bf16_rne(acc[i][j][r] + bv);
      }
    }
  }
}

// ------------- aggregation: U[:,out] = A * U[:,in]; scalar chain -----------
// SMODE 0: none; 1: sout = sum w (d = A*1); 2: sout = sum w*sprev[src]
// 4-edge unroll: 4 outstanding 256B row-gathers per wave.
template <int SMODE>
__global__ __launch_bounds__(256) void agg_k(
    const int* __restrict__ rowp, const int2* __restrict__ csr,
    unsigned int* __restrict__ U32, int co_in, int co_out,
    const float* __restrict__ sprev, float* __restrict__ sout, int n) {
  const int lane = threadIdx.x & 63;
  const int node = (blockIdx.x << 2) + (threadIdx.x >> 6);
  if (node >= n) return;
  const int RS = KTOT / 2;   // 320 uints per row
  int beg = rowp[node], end = rowp[node + 1];
  float ax = 0.f, ay = 0.f, sacc = 0.f;
  const unsigned int* in = U32 + co_in + lane;
  int j = beg;
  for (; j + 3 < end; j += 4) {
    int2 e0 = csr[j], e1 = csr[j + 1], e2 = csr[j + 2], e3 = csr[j + 3];
    unsigned int v0 = in[(size_t)e0.x * RS];
    unsigned int v1 = in[(size_t)e1.x * RS];
    unsigned int v2 = in[(size_t)e2.x * RS];
    unsigned int v3 = in[(size_t)e3.x * RS];
    float w0 = __int_as_float(e0.y), w1 = __int_as_float(e1.y);
    float w2 = __int_as_float(e2.y), w3 = __int_as_float(e3.y);
    ax += w0 * bf16_lo_f(v0) + w1 * bf16_lo_f(v1) +
          w2 * bf16_lo_f(v2) + w3 * bf16_lo_f(v3);
    ay += w0 * bf16_hi_f(v0) + w1 * bf16_hi_f(v1) +
          w2 * bf16_hi_f(v2) + w3 * bf16_hi_f(v3);
    if (SMODE == 1) sacc += (w0 + w1) + (w2 + w3);
    if (SMODE == 2) sacc += w0 * sprev[e0.x] + w1 * sprev[e1.x] +
                            w2 * sprev[e2.x] + w3 * sprev[e3.x];
  }
  for (; j < end; ++j) {
    int2 e0 = csr[j];
    float w0 = __int_as_float(e0.y);
    unsigned int v0 = in[(size_t)e0.x * RS];
    ax += w0 * bf16_lo_f(v0);
    ay += w0 * bf16_hi_f(v0);
    if (SMODE == 1) sacc += w0;
    if (SMODE == 2) sacc += w0 * sprev[e0.x];
  }
  U32[(size_t)node * RS + co_out + lane] =
      (unsigned int)bf16_rne(ax) | ((unsigned int)bf16_rne(ay) << 16);
  if (SMODE != 0 && lane == 0) sout[node] = sacc;
}

// ------ final fused GEMM: out = U[M,640] @ P[640,40] + rank-1 terms --------
__global__ __launch_bounds__(256) void final_gemm_k(
    const unsigned short* __restrict__ U, const unsigned short* __restrict__ Pbf,
    const float* __restrict__ dvec, const float* __restrict__ evec,
    const float* __restrict__ fvec, const float* __restrict__ rv,
    float* __restrict__ out, int M) {
  constexpr int K = KTOT, BK = 64;
  __shared__ __align__(16) unsigned short As[128][BK];
  __shared__ __align__(16) unsigned short Bs[NPAD][BK];
  const int t = threadIdx.x;
  const int lane = t & 63;
  const int q = lane >> 4;
  const int l15 = lane & 15;
  const int w = t >> 6;
  const int m0 = blockIdx.x * 128;

  f32x4 acc[2][3];
#pragma unroll
  for (int i = 0; i < 2; ++i)
#pragma unroll
    for (int j = 0; j < 3; ++j) acc[i][j] = (f32x4){0.f, 0.f, 0.f, 0.f};

  for (int k0 = 0; k0 < K; k0 += BK) {
#pragma unroll
    for (int it = 0; it < 4; ++it) {
      int id = t + it * 256;
      int r = id >> 3, kc = id & 7;
      int gm = m0 + r; if (gm >= M) gm = M - 1;
      uint4 v = *(const uint4*)&U[(size_t)gm * K + k0 + (kc << 3)];
      *(uint4*)&As[r][(kc ^ (r & 7)) << 3] = v;
    }
    for (int id = t; id < NPAD * 8; id += 256) {
      int nn = id >> 3, kc = id & 7;
      uint4 v = *(const uint4*)&Pbf[(size_t)nn * K + k0 + (kc << 3)];
      *(uint4*)&Bs[nn][(kc ^ (nn & 7)) << 3] = v;
    }
    __syncthreads();
#pragma unroll
    for (int kk = 0; kk < 2; ++kk) {
      bf16x8 af[2], bfr[3];
      int kc = (kk << 2) + q;
#pragma unroll
      for (int i = 0; i < 2; ++i) {
        int m = (w << 5) + (i << 4) + l15;
        af[i] = *(const bf16x8*)&As[m][(kc ^ (m & 7)) << 3];
      }
#pragma unroll
      for (int j = 0; j < 3; ++j) {
        int nn = (j << 4) + l15;
        bfr[j] = *(const bf16x8*)&Bs[nn][(kc ^ (nn & 7)) << 3];
      }
#pragma unroll
      for (int i = 0; i < 2; ++i)
#pragma unroll
        for (int j = 0; j < 3; ++j)
          acc[i][j] = __builtin_amdgcn_mfma_f32_16x16x32_bf16(af[i], bfr[j], acc[i][j], 0, 0, 0);
    }
    __syncthreads();
  }
#pragma unroll
  for (int j = 0; j < 3; ++j) {
    int col = (j << 4) + l15;
    if (col >= C_OUT) continue;
    float r1 = rv[0 * 40 + col], rd = rv[1 * 40 + col];
    float re = rv[2 * 40 + col], rf = rv[3 * 40 + col];
#pragma unroll
    for (int i = 0; i < 2; ++i) {
      int rb = m0 + (w << 5) + (i << 4) + (q << 2);
#pragma unroll
      for (int r = 0; r < 4; ++r) {
        int row = rb + r;
        if (row < M) {
          float v = acc[i][j][r] + r1 +
                    dvec[row] * rd + evec[row] * re + fvec[row] * rf;
          out[(size_t)row * C_OUT + col] = v;
        }
      }
    }
  }
}

// ------------------------------- launcher ----------------------------------

extern "C" void kernel_launch(void* const* d_in, const int* in_sizes, int n_in,
                              void* d_out, int out_size, void* d_ws, size_t ws_size,
                              hipStream_t stream) {
  const float* x     = (const float*)d_in[0];
  const int*   eidx  = (const int*)  d_in[1];
  const float* ew    = (const float*)d_in[2];
  const float* W_in  = (const float*)d_in[3];
  const float* b_in  = (const float*)d_in[4];
  const float* W_gcn = (const float*)d_in[5];
  const float* b_gcn = (const float*)d_in[6];
  const float* W_out = (const float*)d_in[7];
  const float* b_out = (const float*)d_in[8];
  float* out = (float*)d_out;

  const int* src = eidx;
  const int* dst = eidx + N_EDGES;

  char* ws = (char*)d_ws;
  size_t off = 0;
  auto alloc = [&](size_t bytes) -> void* {
    void* p = ws + off;
    off += (bytes + 255) & ~(size_t)255;
    return p;
  };
  unsigned long long* acc = (unsigned long long*)alloc((size_t)N_NODES * 8);
  int*   pos    = (int*)  alloc((size_t)N_EDGES * 4);
  int*   cnt    = (int*)  alloc((size_t)N_NODES * 4);
  int*   rowp   = (int*)  alloc((size_t)(N_NODES + 1) * 4);
  float* dinv   = (float*)alloc((size_t)N_NODES * 4);
  int*   bsum   = (int*)  alloc((size_t)256 * 4);
  int2*  csr    = (int2*) alloc((size_t)TOT_E * 8);
  unsigned short* Wt_in = (unsigned short*)alloc((size_t)F_IN * H_DIM * 2);
  unsigned short* Pbf   = (unsigned short*)alloc((size_t)NPAD * KTOT * 2);
  unsigned short* U     = (unsigned short*)alloc((size_t)N_NODES * KTOT * 2);
  float* dvec   = (float*)alloc((size_t)N_NODES * 4);
  float* evec   = (float*)alloc((size_t)N_NODES * 4);
  float* fvec   = (float*)alloc((size_t)N_NODES * 4);
  float* rv     = (float*)alloc((size_t)4 * 40 * 4);
  (void)ws_size; (void)in_sizes; (void)n_in; (void)out_size;

  dim3 b256(256);
  const int NB = (N_NODES + 255) / 256;
  const int GB64 = (N_NODES + 63) / 64;     // 782 blocks for input GEMM
  const int GB = (N_NODES + 127) / 128;     // 391 blocks for final GEMM
  const int AB = (N_NODES + 3) / 4;
  unsigned int* U32 = (unsigned int*)U;

  hipMemsetAsync(acc, 0, (size_t)N_NODES * 8, stream);
  hipMemsetAsync(rv, 0, (size_t)4 * 40 * 4, stream);
  hipMemsetAsync(Pbf, 0, (size_t)NPAD * KTOT * 2, stream);  // pad cols 40..47 = 0

  edge_pass1_k<<<(N_EDGES + 255) / 256, b256, 0, stream>>>(dst, ew, acc, pos, N_EDGES);
  node_pass_k<<<NB, b256, 0, stream>>>(acc, dinv, cnt, N_NODES);
  block_reduce_k<<<NB, b256, 0, stream>>>(cnt, bsum, N_NODES);
  scan_bsums_k<<<1, b256, 0, stream>>>(bsum, NB);
  scan_write_k<<<NB, b256, 0, stream>>>(cnt, bsum, rowp, N_NODES);
  scatter2_k<<<(TOT_E + 255) / 256, b256, 0, stream>>>(src, dst, ew, pos, dinv, rowp,
                                                       csr, N_EDGES, N_NODES);

  wcast_k<<<(F_IN * H_DIM + 255) / 256, b256, 0, stream>>>(W_in, Wt_in, F_IN, F_IN * H_DIM);
  chains_k<<<dim3(10, 4), b256, 0, stream>>>(W_gcn, b_gcn, W_out, b_out, Pbf, rv);

  // U[:,0:128] = bf16(x @ W_in + b_in)
  mfma_gemm_in_k<<<GB64, b256, 0, stream>>>(x, Wt_in, b_in, U, N_NODES);

  // u-chain: u_{p} = A * u_{p-1}; scalar chain d = A*1, e = A*d, f = A*e
  agg_k<1><<<AB, b256, 0, stream>>>(rowp, csr, U32, 0,   64,  nullptr, dvec, N_NODES);
  agg_k<2><<<AB, b256, 0, stream>>>(rowp, csr, U32, 64,  128, dvec,    evec, N_NODES);
  agg_k<2><<<AB, b256, 0, stream>>>(rowp, csr, U32, 128, 192, evec,    fvec, N_NODES);
  agg_k<0><<<AB, b256, 0, stream>>>(rowp, csr, U32, 192, 256, nullptr, nullptr, N_NODES);

  final_gemm_k<<<GB, b256, 0, stream>>>(U, Pbf, dvec, evec, fvec, rv, out, N_NODES);
}

// Round 9
// 479.398 us; speedup vs baseline: 3.2290x; 1.0315x over previous
//
#include <hip/hip_runtime.h>
#include <cstdint>
#include <cstddef>

#define N_NODES 50000
#define N_EDGES 800000
#define F_IN    512
#define H_DIM   128
#define C_OUT   40
#define TOT_E   (N_EDGES + N_NODES)
#define KTOT    640             // h | u1 | u2 | u3 | u4
#define NPAD    48              // 40 cols padded to 3 MFMA tiles

typedef __attribute__((ext_vector_type(8))) __bf16 bf16x8;
typedef __attribute__((ext_vector_type(4))) float f32x4;

__device__ __forceinline__ unsigned short bf16_rne(float f) {
  unsigned int u = __float_as_uint(f);
  u += 0x7fffu + ((u >> 16) & 1u);
  return (unsigned short)(u >> 16);
}
__device__ __forceinline__ float bf16_lo_f(unsigned int u) { return __uint_as_float(u << 16); }
__device__ __forceinline__ float bf16_hi_f(unsigned int u) { return __uint_as_float(u & 0xffff0000u); }

// ----------------------------- setup kernels -------------------------------
// Single u64 atomic per edge: bits [40..63] = count, [0..39] = 2^-24 fixed-pt
// weighted degree. Returned old count = slot of edge in its dst bucket.

__global__ void edge_pass1_k(const int* __restrict__ dst, const float* __restrict__ ew,
                             unsigned long long* __restrict__ acc,
                             int* __restrict__ pos, int e) {
  int i = blockIdx.x * blockDim.x + threadIdx.x;
  if (i < e) {
    int d = dst[i];
    unsigned long long v = (1ull << 40) |
        (unsigned long long)(ew[i] * 16777216.0f + 0.5f);
    unsigned long long old = atomicAdd(&acc[d], v);
    pos[i] = (int)(old >> 40);
  }
}

__global__ void node_pass_k(const unsigned long long* __restrict__ acc,
                            float* __restrict__ dinv, int* __restrict__ cnt, int n) {
  int i = blockIdx.x * blockDim.x + threadIdx.x;
  if (i < n) {
    unsigned long long a = acc[i];
    double dfix = (double)(a & 0xFFFFFFFFFFull);
    float deg = (float)(dfix * (1.0 / 16777216.0) + 1.0);   // +1 self-loop
    dinv[i] = rsqrtf(deg);
    cnt[i] = (int)(a >> 40) + 1;                            // +1 self-loop
  }
}

__global__ __launch_bounds__(256) void block_reduce_k(const int* __restrict__ cnt,
                                                      int* bsum, int n) {
  __shared__ int s[256];
  int t = threadIdx.x;
  int i = blockIdx.x * 256 + t;
  s[t] = (i < n) ? cnt[i] : 0;
  __syncthreads();
  for (int off = 128; off; off >>= 1) {
    if (t < off) s[t] += s[t + off];
    __syncthreads();
  }
  if (t == 0) bsum[blockIdx.x] = s[0];
}

__global__ __launch_bounds__(256) void scan_bsums_k(int* bsum, int nb) {
  __shared__ int s[256];
  int t = threadIdx.x;
  s[t] = (t < nb) ? bsum[t] : 0;
  __syncthreads();
  for (int off = 1; off < 256; off <<= 1) {
    int v = (t >= off) ? s[t - off] : 0;
    __syncthreads();
    s[t] += v;
    __syncthreads();
  }
  if (t < nb) bsum[t] = (t == 0) ? 0 : s[t - 1];
}

__global__ __launch_bounds__(256) void scan_write_k(const int* __restrict__ cnt,
                                                    const int* __restrict__ bsum,
                                                    int* row_ptr, int n) {
  __shared__ int s[256];
  int t = threadIdx.x;
  int i = blockIdx.x * 256 + t;
  int c = (i < n) ? cnt[i] : 0;
  s[t] = c;
  __syncthreads();
  for (int off = 1; off < 256; off <<= 1) {
    int v = (t >= off) ? s[t - off] : 0;
    __syncthreads();
    s[t] += v;
    __syncthreads();
  }
  int ex = bsum[blockIdx.x] + ((t == 0) ? 0 : s[t - 1]);
  if (i < n) row_ptr[i] = ex;
  if (i == n - 1) row_ptr[n] = ex + c;
}

__global__ void scatter2_k(const int* __restrict__ src, const int* __restrict__ dst,
                           const float* __restrict__ ew, const int* __restrict__ pos,
                           const float* __restrict__ dinv, const int* __restrict__ rowp,
                           int2* __restrict__ csr, int e, int n) {
  int i = blockIdx.x * blockDim.x + threadIdx.x;
  if (i < e) {
    int s = src[i], d = dst[i];
    float w = dinv[s] * ew[i] * dinv[d];
    csr[rowp[d] + pos[i]] = make_int2(s, __float_as_int(w));
  } else if (i < e + n) {
    int v = i - e;
    float di = dinv[v];
    csr[rowp[v + 1] - 1] = make_int2(v, __float_as_int(di * di));  // self-loop last
  }
}

// ------------------- weight transpose+cast: Wt[n][k] = bf16(W[k][n]) -------
__global__ void wcast_k(const float* __restrict__ W, unsigned short* __restrict__ Wt,
                        int K, int total) {
  int i = blockIdx.x * 256 + threadIdx.x;
  if (i >= total) return;
  int per = K * 128;
  int b = i / per;
  int rem = i - b * per;
  int k = rem >> 7, nn = rem & 127;
  Wt[(size_t)b * per + (size_t)nn * K + k] = bf16_rne(W[i]);
}

// ---- weight-chain precompute: P slices [KTOT x 48] bf16 + rank-1 rows -----
// Column-parallel: grid (10, 4). blockIdx.y = branch b (j=b+1), blockIdx.x =
// column group (4 of 40 cols). Each block evolves a 128x4 slice S <- W_k * S.
__global__ __launch_bounds__(256) void chains_k(
    const float* __restrict__ W_gcn, const float* __restrict__ b_gcn,
    const float* __restrict__ W_out, const float* __restrict__ b_out,
    unsigned short* __restrict__ Pbf, float* __restrict__ rv) {
  __shared__ float T0[128 * 4];
  __shared__ float T1[128 * 4];
  const int b = blockIdx.y;          // 0..3
  const int j = b + 1;
  const int c0 = blockIdx.x * 4;     // col group base
  const int ks_all[4][4] = {{0, -1, -1, -1}, {1, 2, -1, -1}, {3, 4, 5, -1}, {6, 7, 8, 9}};
  const int t = threadIdx.x;
  const int lane = t & 63;
  const int wv = t >> 6;             // wave 0..3

  for (int idx = t; idx < 512; idx += 256) {
    int r = idx >> 2, c = idx & 3;
    T0[idx] = W_out[(size_t)(j * 128 + r) * 40 + c0 + c];
  }
  __syncthreads();
  float* Tc = T0;
  float* Tn = T1;
  for (int step = 0; step < j; ++step) {
    int kw = ks_all[b][j - 1 - step];
    {
      float s = b_gcn[kw * 128 + lane] * Tc[lane * 4 + wv] +
                b_gcn[kw * 128 + 64 + lane] * Tc[(64 + lane) * 4 + wv];
      for (int o = 32; o; o >>= 1) s += __shfl_down(s, o);
      if (lane == 0) atomicAdd(&rv[step * 40 + c0 + wv], s);
    }
    const float* W = W_gcn + (size_t)kw * 128 * 128;
    int r = t & 127;
    int ch = (t >> 7) << 1;          // 0 or 2
    float a0 = 0.f, a1 = 0.f;
    for (int k = 0; k < 128; k += 4) {
      float4 w4 = *(const float4*)&W[(size_t)r * 128 + k];
      a0 += w4.x * Tc[(k + 0) * 4 + ch] + w4.y * Tc[(k + 1) * 4 + ch] +
            w4.z * Tc[(k + 2) * 4 + ch] + w4.w * Tc[(k + 3) * 4 + ch];
      a1 += w4.x * Tc[(k + 0) * 4 + ch + 1] + w4.y * Tc[(k + 1) * 4 + ch + 1] +
            w4.z * Tc[(k + 2) * 4 + ch + 1] + w4.w * Tc[(k + 3) * 4 + ch + 1];
    }
    Tn[r * 4 + ch] = a0;
    Tn[r * 4 + ch + 1] = a1;
    __syncthreads();
    float* tmp = Tc; Tc = Tn; Tn = tmp;
  }
  for (int idx = t; idx < 512; idx += 256) {
    int r = idx >> 2, c = idx & 3;
    Pbf[(size_t)(c0 + c) * KTOT + j * 128 + r] = bf16_rne(Tc[idx]);
  }
  if (b == 0) {
    for (int idx = t; idx < 512; idx += 256) {
      int r = idx >> 2, c = idx & 3;
      Pbf[(size_t)(c0 + c) * KTOT + r] = bf16_rne(W_out[(size_t)r * 40 + c0 + c]);
    }
    if (blockIdx.x == 0 && t < 40) atomicAdd(&rv[t], b_out[t]);   // row_1 += b_out
  }
}

// ------------- input MFMA GEMM: U[:,0:128] = bf16(x @ W_in + b_in) ---------
// 64x128 tile, BK=64, register-prefetch pipeline.
// amdgpu_waves_per_eu(4,4): round-8 showed __launch_bounds__(256,4) only sets
// the MIN waves/EU (VGPR cap) -- the scheduler still TARGETED 8 waves/EU
// (VGPR_Count=60 < 64, the 8-wave budget) and spilled the prefetch regs to
// scratch to get there (WRITE_SIZE 82 MB). Pinning min=max=4 removes the
// incentive: occupancy can't exceed 4 waves/EU, RA budget 128 VGPR, no spill.
__global__ __launch_bounds__(256)
__attribute__((amdgpu_waves_per_eu(4, 4)))
void mfma_gemm_in_k(
    const float* __restrict__ A, const unsigned short* __restrict__ Wt,
    const float* __restrict__ bias, unsigned short* __restrict__ C, int M) {
  constexpr int K = F_IN, BK = 64;
  __shared__ __align__(16) unsigned short As[64][BK];
  __shared__ __align__(16) unsigned short Bs[128][BK];
  const int t = threadIdx.x;
  const int lane = t & 63;
  const int q = lane >> 4;
  const int l15 = lane & 15;
  const int w = t >> 6;
  const int wm = w >> 1, wn = w & 1;
  const int m0 = blockIdx.x * 64;

  int agm[4];
#pragma unroll
  for (int it = 0; it < 4; ++it) {
    int id = t + it * 256;
    int gm = m0 + (id >> 4); if (gm >= M) gm = M - 1;
    agm[it] = gm;
  }

  float4 a_reg[4];
  uint4  b_reg[4];
  // prologue: prefetch tile 0
#pragma unroll
  for (int it = 0; it < 4; ++it) {
    int f4 = (t + it * 256) & 15;
    a_reg[it] = *(const float4*)&A[(size_t)agm[it] * K + (f4 << 2)];
  }
#pragma unroll
  for (int it = 0; it < 4; ++it) {
    int id = t + it * 256;
    int nn = id >> 3, kc = id & 7;
    b_reg[it] = *(const uint4*)&Wt[(size_t)nn * K + (kc << 3)];
  }

  f32x4 acc[2][4];
#pragma unroll
  for (int i = 0; i < 2; ++i)
#pragma unroll
    for (int j = 0; j < 4; ++j) acc[i][j] = (f32x4){0.f, 0.f, 0.f, 0.f};

  for (int k0 = 0; k0 < K; k0 += BK) {
    // ---- commit prefetched regs to LDS (cast A fp32->bf16) ----
#pragma unroll
    for (int it = 0; it < 4; ++it) {
      int id = t + it * 256;
      int r = id >> 4, f4 = id & 15;
      float4 a = a_reg[it];
      unsigned int u0 = (unsigned int)bf16_rne(a.x) | ((unsigned int)bf16_rne(a.y) << 16);
      unsigned int u1 = (unsigned int)bf16_rne(a.z) | ((unsigned int)bf16_rne(a.w) << 16);
      int kc = f4 >> 1, half = f4 & 1;
      *(uint2*)&As[r][((kc ^ (r & 7)) << 3) + (half << 2)] = make_uint2(u0, u1);
    }
#pragma unroll
    for (int it = 0; it < 4; ++it) {
      int id = t + it * 256;
      int nn = id >> 3, kc = id & 7;
      *(uint4*)&Bs[nn][(kc ^ (nn & 7)) << 3] = b_reg[it];
    }
    __syncthreads();
    // ---- issue next tile's loads; waitcnt lands before next LDS store ----
    if (k0 + BK < K) {
      int kn = k0 + BK;
#pragma unroll
      for (int it = 0; it < 4; ++it) {
        int f4 = (t + it * 256) & 15;
        a_reg[it] = *(const float4*)&A[(size_t)agm[it] * K + kn + (f4 << 2)];
      }
#pragma unroll
      for (int it = 0; it < 4; ++it) {
        int id = t + it * 256;
        int nn = id >> 3, kc = id & 7;
        b_reg[it] = *(const uint4*)&Wt[(size_t)nn * K + kn + (kc << 3)];
      }
    }
    // ---- compute from LDS (overlaps the loads above) ----
#pragma unroll
    for (int kk = 0; kk < 2; ++kk) {
      bf16x8 af[2], bfr[4];
      int kc = (kk << 2) + q;
#pragma unroll
      for (int i = 0; i < 2; ++i) {
        int m = (wm << 5) + (i << 4) + l15;
        af[i] = *(const bf16x8*)&As[m][(kc ^ (m & 7)) << 3];
      }
#pragma unroll
      for (int j = 0; j < 4; ++j) {
        int nn = (wn << 6) + (j << 4) + l15;
        bfr[j] = *(const bf16x8*)&Bs[nn][(kc ^ (nn & 7)) << 3];
      }
#pragma unroll
      for (int i = 0; i < 2; ++i)
#pragma unroll
        for (int j = 0; j < 4; ++j)
          acc[i][j] = __builtin_amdgcn_mfma_f32_16x16x32_bf16(af[i], bfr[j], acc[i][j], 0, 0, 0);
    }
    __syncthreads();
  }
#pragma unroll
  for (int j = 0; j < 4; ++j) {
    int col = (wn << 6) + (j << 4) + l15;
    float bv = bias[col];
#pragma unroll
    for (int i = 0; i < 2; ++i) {
      int rb = m0 + (wm << 5) + (i << 4) + (q << 2);
#pragma unroll
      for (int r = 0; r < 4; ++r) {
        int row = rb + r;
        if (row < M) C[(size_t)row * KTOT + col] = bf16_rne(acc[i][j][r] + bv);
      }
    }
  }
}

// ------------- aggregation: U[:,out] = A * U[:,in]; scalar chain -----------
// SMODE 0: none; 1: sout = sum w (d = A*1); 2: sout = sum w*sprev[src]
// 4-edge unroll: 4 outstanding 256B row-gathers per wave.
template <int SMODE>
__global__ __launch_bounds__(256) void agg_k(
    const int* __restrict__ rowp, const int2* __restrict__ csr,
    unsigned int* __restrict__ U32, int co_in, int co_out,
    const float* __restrict__ sprev, float* __restrict__ sout, int n) {
  const int lane = threadIdx.x & 63;
  const int node = (blockIdx.x << 2) + (threadIdx.x >> 6);
  if (node >= n) return;
  const int RS = KTOT / 2;   // 320 uints per row
  int beg = rowp[node], end = rowp[node + 1];
  float ax = 0.f, ay = 0.f, sacc = 0.f;
  const unsigned int* in = U32 + co_in + lane;
  int j = beg;
  for (; j + 3 < end; j += 4) {
    int2 e0 = csr[j], e1 = csr[j + 1], e2 = csr[j + 2], e3 = csr[j + 3];
    unsigned int v0 = in[(size_t)e0.x * RS];
    unsigned int v1 = in[(size_t)e1.x * RS];
    unsigned int v2 = in[(size_t)e2.x * RS];
    unsigned int v3 = in[(size_t)e3.x * RS];
    float w0 = __int_as_float(e0.y), w1 = __int_as_float(e1.y);
    float w2 = __int_as_float(e2.y), w3 = __int_as_float(e3.y);
    ax += w0 * bf16_lo_f(v0) + w1 * bf16_lo_f(v1) +
          w2 * bf16_lo_f(v2) + w3 * bf16_lo_f(v3);
    ay += w0 * bf16_hi_f(v0) + w1 * bf16_hi_f(v1) +
          w2 * bf16_hi_f(v2) + w3 * bf16_hi_f(v3);
    if (SMODE == 1) sacc += (w0 + w1) + (w2 + w3);
    if (SMODE == 2) sacc += w0 * sprev[e0.x] + w1 * sprev[e1.x] +
                            w2 * sprev[e2.x] + w3 * sprev[e3.x];
  }
  for (; j < end; ++j) {
    int2 e0 = csr[j];
    float w0 = __int_as_float(e0.y);
    unsigned int v0 = in[(size_t)e0.x * RS];
    ax += w0 * bf16_lo_f(v0);
    ay += w0 * bf16_hi_f(v0);
    if (SMODE == 1) sacc += w0;
    if (SMODE == 2) sacc += w0 * sprev[e0.x];
  }
  U32[(size_t)node * RS + co_out + lane] =
      (unsigned int)bf16_rne(ax) | ((unsigned int)bf16_rne(ay) << 16);
  if (SMODE != 0 && lane == 0) sout[node] = sacc;
}

// ------ final fused GEMM: out = U[M,640] @ P[640,40] + rank-1 terms --------
__global__ __launch_bounds__(256) void final_gemm_k(
    const unsigned short* __restrict__ U, const unsigned short* __restrict__ Pbf,
    const float* __restrict__ dvec, const float* __restrict__ evec,
    const float* __restrict__ fvec, const float* __restrict__ rv,
    float* __restrict__ out, int M) {
  constexpr int K = KTOT, BK = 64;
  __shared__ __align__(16) unsigned short As[128][BK];
  __shared__ __align__(16) unsigned short Bs[NPAD][BK];
  const int t = threadIdx.x;
  const int lane = t & 63;
  const int q = lane >> 4;
  const int l15 = lane & 15;
  const int w = t >> 6;
  const int m0 = blockIdx.x * 128;

  f32x4 acc[2][3];
#pragma unroll
  for (int i = 0; i < 2; ++i)
#pragma unroll
    for (int j = 0; j < 3; ++j) acc[i][j] = (f32x4){0.f, 0.f, 0.f, 0.f};

  for (int k0 = 0; k0 < K; k0 += BK) {
#pragma unroll
    for (int it = 0; it < 4; ++it) {
      int id = t + it * 256;
      int r = id >> 3, kc = id & 7;
      int gm = m0 + r; if (gm >= M) gm = M - 1;
      uint4 v = *(const uint4*)&U[(size_t)gm * K + k0 + (kc << 3)];
      *(uint4*)&As[r][(kc ^ (r & 7)) << 3] = v;
    }
    for (int id = t; id < NPAD * 8; id += 256) {
      int nn = id >> 3, kc = id & 7;
      uint4 v = *(const uint4*)&Pbf[(size_t)nn * K + k0 + (kc << 3)];
      *(uint4*)&Bs[nn][(kc ^ (nn & 7)) << 3] = v;
    }
    __syncthreads();
#pragma unroll
    for (int kk = 0; kk < 2; ++kk) {
      bf16x8 af[2], bfr[3];
      int kc = (kk << 2) + q;
#pragma unroll
      for (int i = 0; i < 2; ++i) {
        int m = (w << 5) + (i << 4) + l15;
        af[i] = *(const bf16x8*)&As[m][(kc ^ (m & 7)) << 3];
      }
#pragma unroll
      for (int j = 0; j < 3; ++j) {
        int nn = (j << 4) + l15;
        bfr[j] = *(const bf16x8*)&Bs[nn][(kc ^ (nn & 7)) << 3];
      }
#pragma unroll
      for (int i = 0; i < 2; ++i)
#pragma unroll
        for (int j = 0; j < 3; ++j)
          acc[i][j] = __builtin_amdgcn_mfma_f32_16x16x32_bf16(af[i], bfr[j], acc[i][j], 0, 0, 0);
    }
    __syncthreads();
  }
#pragma unroll
  for (int j = 0; j < 3; ++j) {
    int col = (j << 4) + l15;
    if (col >= C_OUT) continue;
    float r1 = rv[0 * 40 + col], rd = rv[1 * 40 + col];
    float re = rv[2 * 40 + col], rf = rv[3 * 40 + col];
#pragma unroll
    for (int i = 0; i < 2; ++i) {
      int rb = m0 + (w << 5) + (i << 4) + (q << 2);
#pragma unroll
      for (int r = 0; r < 4; ++r) {
        int row = rb + r;
        if (row < M) {
          float v = acc[i][j][r] + r1 +
                    dvec[row] * rd + evec[row] * re + fvec[row] * rf;
          out[(size_t)row * C_OUT + col] = v;
        }
      }
    }
  }
}

// ------------------------------- launcher ----------------------------------

extern "C" void kernel_launch(void* const* d_in, const int* in_sizes, int n_in,
                              void* d_out, int out_size, void* d_ws, size_t ws_size,
                              hipStream_t stream) {
  const float* x     = (const float*)d_in[0];
  const int*   eidx  = (const int*)  d_in[1];
  const float* ew    = (const float*)d_in[2];
  const float* W_in  = (const float*)d_in[3];
  const float* b_in  = (const float*)d_in[4];
  const float* W_gcn = (const float*)d_in[5];
  const float* b_gcn = (const float*)d_in[6];
  const float* W_out = (const float*)d_in[7];
  const float* b_out = (const float*)d_in[8];
  float* out = (float*)d_out;

  const int* src = eidx;
  const int* dst = eidx + N_EDGES;

  char* ws = (char*)d_ws;
  size_t off = 0;
  auto alloc = [&](size_t bytes) -> void* {
    void* p = ws + off;
    off += (bytes + 255) & ~(size_t)255;
    return p;
  };
  unsigned long long* acc = (unsigned long long*)alloc((size_t)N_NODES * 8);
  int*   pos    = (int*)  alloc((size_t)N_EDGES * 4);
  int*   cnt    = (int*)  alloc((size_t)N_NODES * 4);
  int*   rowp   = (int*)  alloc((size_t)(N_NODES + 1) * 4);
  float* dinv   = (float*)alloc((size_t)N_NODES * 4);
  int*   bsum   = (int*)  alloc((size_t)256 * 4);
  int2*  csr    = (int2*) alloc((size_t)TOT_E * 8);
  unsigned short* Wt_in = (unsigned short*)alloc((size_t)F_IN * H_DIM * 2);
  unsigned short* Pbf   = (unsigned short*)alloc((size_t)NPAD * KTOT * 2);
  unsigned short* U     = (unsigned short*)alloc((size_t)N_NODES * KTOT * 2);
  float* dvec   = (float*)alloc((size_t)N_NODES * 4);
  float* evec   = (float*)alloc((size_t)N_NODES * 4);
  float* fvec   = (float*)alloc((size_t)N_NODES * 4);
  float* rv     = (float*)alloc((size_t)4 * 40 * 4);
  (void)ws_size; (void)in_sizes; (void)n_in; (void)out_size;

  dim3 b256(256);
  const int NB = (N_NODES + 255) / 256;
  const int GB64 = (N_NODES + 63) / 64;     // 782 blocks for input GEMM
  const int GB = (N_NODES + 127) / 128;     // 391 blocks for final GEMM
  const int AB = (N_NODES + 3) / 4;
  unsigned int* U32 = (unsigned int*)U;

  hipMemsetAsync(acc, 0, (size_t)N_NODES * 8, stream);
  hipMemsetAsync(rv, 0, (size_t)4 * 40 * 4, stream);
  hipMemsetAsync(Pbf, 0, (size_t)NPAD * KTOT * 2, stream);  // pad cols 40..47 = 0

  edge_pass1_k<<<(N_EDGES + 255) / 256, b256, 0, stream>>>(dst, ew, acc, pos, N_EDGES);
  node_pass_k<<<NB, b256, 0, stream>>>(acc, dinv, cnt, N_NODES);
  block_reduce_k<<<NB, b256, 0, stream>>>(cnt, bsum, N_NODES);
  scan_bsums_k<<<1, b256, 0, stream>>>(bsum, NB);
  scan_write_k<<<NB, b256, 0, stream>>>(cnt, bsum, rowp, N_NODES);
  scatter2_k<<<(TOT_E + 255) / 256, b256, 0, stream>>>(src, dst, ew, pos, dinv, rowp,
                                                       csr, N_EDGES, N_NODES);

  wcast_k<<<(F_IN * H_DIM + 255) / 256, b256, 0, stream>>>(W_in, Wt_in, F_IN, F_IN * H_DIM);
  chains_k<<<dim3(10, 4), b256, 0, stream>>>(W_gcn, b_gcn, W_out, b_out, Pbf, rv);

  // U[:,0:128] = bf16(x @ W_in + b_in)
  mfma_gemm_in_k<<<GB64, b256, 0, stream>>>(x, Wt_in, b_in, U, N_NODES);

  // u-chain: u_{p} = A * u_{p-1}; scalar chain d = A*1, e = A*d, f = A*e
  agg_k<1><<<AB, b256, 0, stream>>>(rowp, csr, U32, 0,   64,  nullptr, dvec, N_NODES);
  agg_k<2><<<AB, b256, 0, stream>>>(rowp, csr, U32, 64,  128, dvec,    evec, N_NODES);
  agg_k<2><<<AB, b256, 0, stream>>>(rowp, csr, U32, 128, 192, evec,    fvec, N_NODES);
  agg_k<0><<<AB, b256, 0, stream>>>(rowp, csr, U32, 192, 256, nullptr, nullptr, N_NODES);

  final_gemm_k<<<GB, b256, 0, stream>>>(U, Pbf, dvec, evec, fvec, rv, out, N_NODES);
}